// Round 20
// baseline (1570.532 us; speedup 1.0000x reference)
//
#include <hip/hip_runtime.h>

#define DEV __device__ __forceinline__
typedef unsigned short u16;
typedef __bf16 bf16_t;
typedef bf16_t bf16x8 __attribute__((ext_vector_type(8)));
typedef float f32x4 __attribute__((ext_vector_type(4)));

DEV u16 f2bf(float f){ unsigned u=__float_as_uint(f); return (u16)((u + 0x7fffu + ((u>>16)&1u))>>16); }

DEV void gl_lds16(const void* g, void* l){
  __builtin_amdgcn_global_load_lds((__attribute__((address_space(1))) void*)g,
                                   (__attribute__((address_space(3))) void*)l, 16, 0, 0);
}
DEV f32x4 MFMA(bf16x8 a, bf16x8 b, f32x4 c){
  return __builtin_amdgcn_mfma_f32_16x16x32_bf16(a, b, c, 0, 0, 0);
}
DEV bf16x8 ld8(const u16* p){ return *(const bf16x8*)p; }

// ---------------- fused prep: tok_emb f32->bf16 convert + embedding gather
__global__ __launch_bounds__(256) void k_prep(const float* __restrict__ emb,
                                              u16* __restrict__ te,
                                              const int* __restrict__ idx,
                                              float* __restrict__ x){
  int b = blockIdx.x;
  if(b < 32000){
    int i = b*256 + threadIdx.x;          // < 8192000
    float4 v = ((const float4*)emb)[i];
    ushort4 o; o.x=f2bf(v.x); o.y=f2bf(v.y); o.z=f2bf(v.z); o.w=f2bf(v.w);
    ((ushort4*)te)[i] = o;
  } else {
    int row = b - 32000;                  // 0..4095
    int tok = idx[row];
    ((float4*)(x + (size_t)row*1024))[threadIdx.x] =
        ((const float4*)(emb + (size_t)tok*1024))[threadIdx.x];
  }
}

// ---------------- layernorm (fp32 in) -> bf16 out, row = 1024
__global__ __launch_bounds__(256) void k_ln(const float* __restrict__ x,
                                            const float* __restrict__ sc,
                                            const float* __restrict__ bi,
                                            u16* __restrict__ out){
  int row = blockIdx.x;
  const float* xr = x + (size_t)row*1024;
  float4 v = ((const float4*)xr)[threadIdx.x];
  float s = v.x+v.y+v.z+v.w;
  float q = v.x*v.x+v.y*v.y+v.z*v.z+v.w*v.w;
  #pragma unroll
  for(int m=1;m<64;m<<=1){ s += __shfl_xor(s,m); q += __shfl_xor(q,m); }
  __shared__ float ss[4], sq[4];
  int w = threadIdx.x>>6;
  if((threadIdx.x&63)==0){ ss[w]=s; sq[w]=q; }
  __syncthreads();
  s = ss[0]+ss[1]+ss[2]+ss[3];
  q = sq[0]+sq[1]+sq[2]+sq[3];
  float mu = s*(1.f/1024.f);
  float var = q*(1.f/1024.f) - mu*mu;
  float rs = rsqrtf(var + 1e-5f);
  float4 sv = ((const float4*)sc)[threadIdx.x];
  float4 bv = ((const float4*)bi)[threadIdx.x];
  ushort4 o;
  o.x = f2bf((v.x-mu)*rs*sv.x + bv.x);
  o.y = f2bf((v.y-mu)*rs*sv.y + bv.y);
  o.z = f2bf((v.z-mu)*rs*sv.z + bv.z);
  o.w = f2bf((v.w-mu)*rs*sv.w + bv.w);
  *(ushort4*)(out + (size_t)row*1024 + threadIdx.x*4) = o;
}

// ---------------- transpose + convert (64x64, vectorized): W[K][N] f32 -> Wt[N][K] bf16
__global__ __launch_bounds__(256) void k_convT(const float* __restrict__ W,
                                               u16* __restrict__ Wt, int K, int N){
  __shared__ float tile[64][68];
  size_t loff = (size_t)blockIdx.z * K * N;
  W  += loff;  Wt += loff;
  int n0 = blockIdx.x*64, k0 = blockIdx.y*64;
  int tx = threadIdx.x & 15, ty = threadIdx.x >> 4;   // 16 x 16
  #pragma unroll
  for(int r=0;r<4;r++){
    int row = ty + r*16;
    float4 v = *(const float4*)&W[(size_t)(k0+row)*N + n0 + tx*4];
    *(float4*)&tile[row][tx*4] = v;
  }
  __syncthreads();
  int nn = threadIdx.x >> 2, kq = threadIdx.x & 3;
  #pragma unroll
  for(int r=0;r<4;r++){
    int k = (kq + r*4)*4;
    ushort4 o;
    o.x = f2bf(tile[k+0][nn]); o.y = f2bf(tile[k+1][nn]);
    o.z = f2bf(tile[k+2][nn]); o.w = f2bf(tile[k+3][nn]);
    *(ushort4*)&Wt[(size_t)(n0+nn)*K + k0 + k] = o;
  }
}

// ---------------- GEMM 128x128 (2-barrier): C = A * Bt^T, BK=64, XOR swizzle
template<int EPI, int SWAP>
__global__ __launch_bounds__(256) void k_gemm(const u16* __restrict__ A,
                                              const u16* __restrict__ Bt,
                                              const float* __restrict__ bias,
                                              void* __restrict__ out,
                                              float* __restrict__ res,
                                              int M, int N, int K, int m_base){
  __shared__ __align__(16) u16 As[128*64];
  __shared__ __align__(16) u16 Bs[128*64];
  int t = threadIdx.x, l = t & 63, w = t >> 6;
  int g = l >> 4, lr = l & 15;
  int wr = w >> 1, wc = w & 1;
  int m0, n0;
  if constexpr(SWAP){ m0 = m_base + blockIdx.x*128; n0 = blockIdx.y*128; }
  else              { m0 = m_base + blockIdx.y*128; n0 = blockIdx.x*128; }
  f32x4 acc[4][4];
  #pragma unroll
  for(int i=0;i<4;i++)
    #pragma unroll
    for(int j=0;j<4;j++) acc[i][j] = f32x4{0.f,0.f,0.f,0.f};

  int sr = t >> 3;
  int sc = (((t & 7) ^ (sr & 7)) * 8);
  const u16* pa = A  + (size_t)(m0 + sr)*K + sc;
  const u16* pb = Bt + (size_t)(n0 + sr)*K + sc;
  u16* lda = As + t*8;
  u16* ldb = Bs + t*8;
  const int rs_a = (lr & 7)*8;

  for(int k0=0; k0<K; k0+=64){
    #pragma unroll
    for(int i=0;i<4;i++){
      gl_lds16(pa + (size_t)(i*32)*K, lda + i*2048);
      gl_lds16(pb + (size_t)(i*32)*K, ldb + i*2048);
    }
    pa += 64; pb += 64;
    __syncthreads();
    bf16x8 af[4][2], bfr[4][2];
    #pragma unroll
    for(int mi=0;mi<4;mi++){
      int row = wr*64 + mi*16 + lr;
      af[mi][0] = ld8(&As[row*64 + ((g*8     ) ^ rs_a)]);
      af[mi][1] = ld8(&As[row*64 + ((g*8 + 32) ^ rs_a)]);
    }
    #pragma unroll
    for(int ni=0;ni<4;ni++){
      int row = wc*64 + ni*16 + lr;
      bfr[ni][0] = ld8(&Bs[row*64 + ((g*8     ) ^ rs_a)]);
      bfr[ni][1] = ld8(&Bs[row*64 + ((g*8 + 32) ^ rs_a)]);
    }
    #pragma unroll
    for(int mi=0;mi<4;mi++)
      #pragma unroll
      for(int ni=0;ni<4;ni++){
        acc[mi][ni] = MFMA(af[mi][0], bfr[ni][0], acc[mi][ni]);
        acc[mi][ni] = MFMA(af[mi][1], bfr[ni][1], acc[mi][ni]);
      }
    __syncthreads();
  }

  float bv[4];
  #pragma unroll
  for(int ni=0;ni<4;ni++){
    if constexpr(EPI==3) bv[ni] = 0.f;
    else bv[ni] = bias[n0 + wc*64 + ni*16 + lr];
  }
  #pragma unroll
  for(int mi=0;mi<4;mi++){
    int row = m0 + wr*64 + mi*16 + g*4;
    #pragma unroll
    for(int ni=0;ni<4;ni++){
      int col = n0 + wc*64 + ni*16 + lr;
      #pragma unroll
      for(int r=0;r<4;r++){
        float v = acc[mi][ni][r] + bv[ni];
        size_t oidx = (size_t)(row + r)*N + col;
        if constexpr(EPI==0){
          ((u16*)out)[oidx] = f2bf(v);
        } else if constexpr(EPI==1){
          res[oidx] += v;
        } else if constexpr(EPI==2){
          float gv = 0.5f*v*(1.f + erff(v*0.70710678118654752f));
          ((u16*)out)[oidx] = f2bf(gv);
        } else {
          ((float*)out)[oidx] = v;   // f32 logits
        }
      }
    }
  }
}

// ---------------- GEMM 128x64 narrow: high-occupancy even-grid variant
// EPI: 0 = +bias -> bf16 out ; 1 = +bias, res(f32) += v
template<int EPI>
__global__ __launch_bounds__(256) void k_gemm_n64(const u16* __restrict__ A,
                                                  const u16* __restrict__ Bt,
                                                  const float* __restrict__ bias,
                                                  void* __restrict__ outp,
                                                  float* __restrict__ res,
                                                  int M, int N, int K){
  __shared__ __align__(16) u16 As[128*64];
  __shared__ __align__(16) u16 Bs[64*64];
  int t = threadIdx.x, l = t & 63, w = t >> 6;
  int g = l >> 4, lr = l & 15;
  int wr = w >> 1, wc = w & 1;
  int m0 = blockIdx.y*128, n0 = blockIdx.x*64;
  f32x4 acc[4][2];
  #pragma unroll
  for(int i=0;i<4;i++)
    #pragma unroll
    for(int j=0;j<2;j++) acc[i][j] = f32x4{0.f,0.f,0.f,0.f};

  int sr = t >> 3;
  int sc = (((t & 7) ^ (sr & 7)) * 8);
  const u16* pa = A  + (size_t)(m0 + sr)*K + sc;
  const u16* pb = Bt + (size_t)(n0 + sr)*K + sc;
  u16* lda = As + t*8;
  u16* ldb = Bs + t*8;
  const int rs_a = (lr & 7)*8;

  for(int k0=0; k0<K; k0+=64){
    #pragma unroll
    for(int i=0;i<4;i++)
      gl_lds16(pa + (size_t)(i*32)*K, lda + i*2048);
    #pragma unroll
    for(int i=0;i<2;i++)
      gl_lds16(pb + (size_t)(i*32)*K, ldb + i*2048);
    pa += 64; pb += 64;
    __syncthreads();
    bf16x8 af[4][2], bfr[2][2];
    #pragma unroll
    for(int mi=0;mi<4;mi++){
      int row = wr*64 + mi*16 + lr;
      af[mi][0] = ld8(&As[row*64 + ((g*8     ) ^ rs_a)]);
      af[mi][1] = ld8(&As[row*64 + ((g*8 + 32) ^ rs_a)]);
    }
    #pragma unroll
    for(int ni=0;ni<2;ni++){
      int row = wc*32 + ni*16 + lr;
      bfr[ni][0] = ld8(&Bs[row*64 + ((g*8     ) ^ rs_a)]);
      bfr[ni][1] = ld8(&Bs[row*64 + ((g*8 + 32) ^ rs_a)]);
    }
    #pragma unroll
    for(int mi=0;mi<4;mi++)
      #pragma unroll
      for(int ni=0;ni<2;ni++){
        acc[mi][ni] = MFMA(af[mi][0], bfr[ni][0], acc[mi][ni]);
        acc[mi][ni] = MFMA(af[mi][1], bfr[ni][1], acc[mi][ni]);
      }
    __syncthreads();
  }

  float bv[2];
  #pragma unroll
  for(int ni=0;ni<2;ni++) bv[ni] = bias[n0 + wc*32 + ni*16 + lr];
  #pragma unroll
  for(int mi=0;mi<4;mi++){
    int row = m0 + wr*64 + mi*16 + g*4;
    #pragma unroll
    for(int ni=0;ni<2;ni++){
      int col = n0 + wc*32 + ni*16 + lr;
      #pragma unroll
      for(int r=0;r<4;r++){
        float v = acc[mi][ni][r] + bv[ni];
        if constexpr(EPI==0)
          ((u16*)outp)[(size_t)(row + r)*N + col] = f2bf(v);
        else
          res[(size_t)(row + r)*N + col] += v;
      }
    }
  }
}

// ---------------- GEMM 256x256 8-phase (head) — r15 schedule (proven ~350us)
__global__ __launch_bounds__(512) void k_gemm256(const u16* __restrict__ A,
                                                 const u16* __restrict__ Bt,
                                                 float* __restrict__ out,
                                                 int M, int N, int K, int m_base){
  __shared__ __align__(16) u16 As[2][256*64];
  __shared__ __align__(16) u16 Bs[2][256*64];
  int t = threadIdx.x, l = t & 63, wid = t >> 6;
  int g = l >> 4, lr = l & 15;
  int m0 = m_base + blockIdx.x*256, n0 = blockIdx.y*256;
  f32x4 acc[2][16];
  #pragma unroll
  for(int mi=0;mi<2;mi++)
    #pragma unroll
    for(int i=0;i<16;i++) acc[mi][i] = f32x4{0.f,0.f,0.f,0.f};

  int srow = t >> 3;
  int scol = ((t & 7) ^ (srow & 7)) * 8;
  const int rs = (lr & 7) * 8;
  int nt = K >> 6;

  auto stage_half = [&](int jj, int h){
    int buf = jj & 1; int k0s = jj << 6;
    if(h < 2){
      #pragma unroll
      for(int c=0;c<2;c++){
        int rr = h*128 + c*64 + srow;
        gl_lds16(A + (size_t)(m0 + rr)*K + k0s + scol,
                 &As[buf][rr*64 + (t&7)*8]);
      }
    } else {
      #pragma unroll
      for(int c=0;c<2;c++){
        int rr = (h-2)*128 + c*64 + srow;
        gl_lds16(Bt + (size_t)(n0 + rr)*K + k0s + scol,
                 &Bs[buf][rr*64 + (t&7)*8]);
      }
    }
  };

  stage_half(0,0); stage_half(0,1); stage_half(0,2); stage_half(0,3);
  asm volatile("s_waitcnt vmcnt(2)" ::: "memory");
  __builtin_amdgcn_s_barrier();
  __builtin_amdgcn_sched_barrier(0);

  bf16x8 af[2][2];
  for(int j=0; j<nt; ++j){
    const u16* Ab = As[j & 1];
    const u16* Bb = Bs[j & 1];
    bool pf = (j + 1 < nt);
    #pragma unroll
    for(int q=0; q<4; ++q){
      if(q == 0){
        #pragma unroll
        for(int mi=0;mi<2;mi++){
          int row = wid*32 + mi*16 + lr;
          af[mi][0] = ld8(&Ab[row*64 + ((g*8     ) ^ rs)]);
          af[mi][1] = ld8(&Ab[row*64 + ((g*8 + 32) ^ rs)]);
        }
      }
      bf16x8 bfr[4][2];
      #pragma unroll
      for(int i=0;i<4;i++){
        int row = (q*4 + i)*16 + lr;
        bfr[i][0] = ld8(&Bb[row*64 + ((g*8     ) ^ rs)]);
        bfr[i][1] = ld8(&Bb[row*64 + ((g*8 + 32) ^ rs)]);
      }
      if(pf) stage_half(j+1, q);
      __builtin_amdgcn_s_barrier();
      __builtin_amdgcn_sched_barrier(0);
      __builtin_amdgcn_s_setprio(1);
      #pragma unroll
      for(int mi=0;mi<2;mi++)
        #pragma unroll
        for(int i=0;i<4;i++){
          acc[mi][q*4+i] = MFMA(af[mi][0], bfr[i][0], acc[mi][q*4+i]);
          acc[mi][q*4+i] = MFMA(af[mi][1], bfr[i][1], acc[mi][q*4+i]);
        }
      __builtin_amdgcn_s_setprio(0);
      if(q == 1) asm volatile("s_waitcnt vmcnt(4)" ::: "memory");
      if(q == 3) asm volatile("s_waitcnt vmcnt(2)" ::: "memory");
      __builtin_amdgcn_s_barrier();
      __builtin_amdgcn_sched_barrier(0);
    }
  }

  #pragma unroll
  for(int mi=0;mi<2;mi++){
    int row = m0 + wid*32 + mi*16 + g*4;
    #pragma unroll
    for(int i=0;i<16;i++){
      int col = n0 + i*16 + lr;
      #pragma unroll
      for(int r=0;r<4;r++)
        out[(size_t)(row + r)*N + col] = acc[mi][i][r];
    }
  }
}

// ---------------- head GEMM fallback (small-ws only): BK=32 reg-staged B
__global__ __launch_bounds__(256) void k_gemm_f32b(const u16* __restrict__ A,
                                                   const float* __restrict__ B,
                                                   float* __restrict__ out,
                                                   int M, int N, int K, int m_base){
  __shared__ __align__(16) u16 As[128*32];
  __shared__ __align__(16) u16 Bs[128*32];
  int t = threadIdx.x, l = t & 63, w = t >> 6;
  int g = l >> 4, lr = l & 15;
  int wr = w >> 1, wc = w & 1;
  int m0 = m_base + blockIdx.y*128, n0 = blockIdx.x*128;
  f32x4 acc[4][4];
  #pragma unroll
  for(int i=0;i<4;i++)
    #pragma unroll
    for(int j=0;j<4;j++) acc[i][j] = f32x4{0.f,0.f,0.f,0.f};

  int r0 = t >> 2, c0 = (t & 3)*8;
  const u16* pa0 = A + (size_t)(m0 + r0)*K + c0;
  const u16* pa1 = A + (size_t)(m0 + r0 + 64)*K + c0;
  u16* la0 = As + t*8;  u16* la1 = As + (t+256)*8;
  int br = t >> 1, bc = (t & 1)*16;
  const float* pb = B + (size_t)(n0 + br)*K + bc;

  for(int k0=0; k0<K; k0+=32){
    gl_lds16(pa0, la0); gl_lds16(pa1, la1);
    pa0 += 32; pa1 += 32;
    float4 f0 = ((const float4*)pb)[0];
    float4 f1 = ((const float4*)pb)[1];
    float4 f2 = ((const float4*)pb)[2];
    float4 f3 = ((const float4*)pb)[3];
    pb += 32;
    ushort4 u0{f2bf(f0.x),f2bf(f0.y),f2bf(f0.z),f2bf(f0.w)};
    ushort4 u1{f2bf(f1.x),f2bf(f1.y),f2bf(f1.z),f2bf(f1.w)};
    ushort4 u2{f2bf(f2.x),f2bf(f2.y),f2bf(f2.z),f2bf(f2.w)};
    ushort4 u3{f2bf(f3.x),f2bf(f3.y),f2bf(f3.z),f2bf(f3.w)};
    *(ushort4*)&Bs[br*32 + bc +  0] = u0;
    *(ushort4*)&Bs[br*32 + bc +  4] = u1;
    *(ushort4*)&Bs[br*32 + bc +  8] = u2;
    *(ushort4*)&Bs[br*32 + bc + 12] = u3;
    __syncthreads();
    bf16x8 af[4], bfr[4];
    #pragma unroll
    for(int mi=0;mi<4;mi++) af[mi]  = ld8(&As[(wr*64 + mi*16 + lr)*32 + g*8]);
    #pragma unroll
    for(int ni=0;ni<4;ni++) bfr[ni] = ld8(&Bs[(wc*64 + ni*16 + lr)*32 + g*8]);
    #pragma unroll
    for(int mi=0;mi<4;mi++)
      #pragma unroll
      for(int ni=0;ni<4;ni++)
        acc[mi][ni] = MFMA(af[mi], bfr[ni], acc[mi][ni]);
    __syncthreads();
  }

  #pragma unroll
  for(int mi=0;mi<4;mi++){
    int row = m0 + wr*64 + mi*16 + g*4;
    #pragma unroll
    for(int ni=0;ni<4;ni++){
      int col = n0 + wc*64 + ni*16 + lr;
      #pragma unroll
      for(int r=0;r<4;r++)
        out[(size_t)(row + r)*N + col] = acc[mi][ni][r];
    }
  }
}

// ---------------- flash attention, QBLK=128, 4 waves x 32 q-rows (2 frags):
// K/V LDS fragments read ONCE per wave feed both row-fragments' MFMAs
// (0.55 LDS-reads/MFMA vs 1.0) — attacks the LDS-read-throughput bound.
__global__ __launch_bounds__(256) void k_attn(const u16* __restrict__ qkv,
                                              u16* __restrict__ atto){
  __shared__ __align__(16) u16 Ksm[64*72];
  __shared__ __align__(16) u16 Vsm[64*72];
  __shared__ __align__(16) u16 Psm[4][32*72];
  int t = threadIdx.x, l = t & 63, w = t >> 6, g = l >> 4, lr = l & 15;
  int bh = blockIdx.y; int b = bh >> 4, h = bh & 15, kvh = h >> 2;
  int qb = blockIdx.x * 128;
  const float L2E = 1.44269504088896f;
  const float C1  = 0.125f * L2E;
  float slopeL = exp2f(-0.5f*(float)(h+1)) * L2E;
  float sLkt[4];
  #pragma unroll
  for(int kt=0;kt<4;kt++) sLkt[kt] = slopeL*(float)(kt*16+lr);

  // two Q fragments: rows qb + w*32 + {0,16} + lr
  const u16* qp0 = qkv + (size_t)(b*2048 + qb + w*32 + lr)*1536 + h*64;
  const u16* qp1 = qp0 + (size_t)16*1536;
  bf16x8 qA0 = ld8(qp0 + g*8),  qA1 = ld8(qp0 + 32 + g*8);
  bf16x8 qB0 = ld8(qp1 + g*8),  qB1 = ld8(qp1 + 32 + g*8);

  bf16_t onev = (bf16_t)1.0f;
  bf16x8 onesb = {onev,onev,onev,onev,onev,onev,onev,onev};

  f32x4 oaccA[4], oaccB[4];
  #pragma unroll
  for(int i=0;i<4;i++){ oaccA[i] = f32x4{0.f,0.f,0.f,0.f}; oaccB[i] = f32x4{0.f,0.f,0.f,0.f}; }
  f32x4 lsumA = f32x4{0.f,0.f,0.f,0.f}, lsumB = f32x4{0.f,0.f,0.f,0.f};

  int qmin_w = qb + w*32;
  int qmax_w = qmin_w + 31;
  int nkb = blockIdx.x*2 + 2;
  for(int kb=0; kb<nkb; kb++){
    __syncthreads();
    // K stage (r13-verified): 256 threads x 2 int4
    #pragma unroll
    for(int i=0;i<2;i++){
      int tt = t + i*256;
      int key = tt >> 3, ho = (tt & 7)*8;
      const u16* src = qkv + (size_t)(b*2048 + kb*64 + key)*1536 + 1024 + kvh*64 + ho;
      *(int4*)&Ksm[key*72 + ho] = *(const int4*)src;
    }
    // V stage transposed+swizzled (r13-verified)
    {
      int key0 = (t>>3)*2, hd0 = (t&7)*8;
      const u16* v0 = qkv + (size_t)(b*2048 + kb*64 + key0)*1536 + 1280 + kvh*64 + hd0;
      int4 A0 = *(const int4*)v0;
      int4 A1 = *(const int4*)(v0 + 1536);
      const u16* ua = (const u16*)&A0; const u16* ub = (const u16*)&A1;
      #pragma unroll
      for(int j=0;j<8;j++){
        int row = hd0 + j;
        int colp = key0 ^ ((row>>3)*8);
        unsigned pr = (unsigned)ua[j] | ((unsigned)ub[j]<<16);
        *(unsigned*)&Vsm[row*72 + colp] = pr;
      }
    }
    __syncthreads();
    if(kb*64 > qmax_w) continue;
    // S = Q K^T for both fragments; K fragments read once
    f32x4 sA[4], sB[4];
    #pragma unroll
    for(int kt=0;kt<4;kt++){ sA[kt] = f32x4{0.f,0.f,0.f,0.f}; sB[kt] = f32x4{0.f,0.f,0.f,0.f}; }
    #pragma unroll
    for(int kt=0;kt<4;kt++){
      bf16x8 kf0 = ld8(&Ksm[(kt*16+lr)*72 + g*8]);
      bf16x8 kf1 = ld8(&Ksm[(kt*16+lr)*72 + 32 + g*8]);
      sA[kt] = MFMA(qA0, kf0, sA[kt]);  sA[kt] = MFMA(qA1, kf1, sA[kt]);
      sB[kt] = MFMA(qB0, kf0, sB[kt]);  sB[kt] = MFMA(qB1, kf1, sB[kt]);
    }
    // softmax -> Psm (frag f occupies rows f*16..f*16+15 of wave region)
    if(kb*64 + 63 <= qmin_w){
      #pragma unroll
      for(int r=0;r<4;r++){
        int qA = qb + w*32 + g*4 + r;
        float baseA = slopeL*(float)(kb*64 - qA) - 8.0f*L2E;
        float baseB = baseA - slopeL*16.0f;
        #pragma unroll
        for(int kt=0;kt<4;kt++){
          float fA = fmaf(sA[kt][r], C1, baseA + sLkt[kt]);
          float fB = fmaf(sB[kt][r], C1, baseB + sLkt[kt]);
          Psm[w][(g*4+r)*72 + kt*16 + lr]      = f2bf(exp2f(fA));
          Psm[w][(16 + g*4+r)*72 + kt*16 + lr] = f2bf(exp2f(fB));
        }
      }
    } else {
      #pragma unroll
      for(int r=0;r<4;r++){
        int qA = qb + w*32 + g*4 + r;
        int qB = qA + 16;
        float baseA = slopeL*(float)(kb*64 - qA) - 8.0f*L2E;
        float baseB = baseA - slopeL*16.0f;
        #pragma unroll
        for(int kt=0;kt<4;kt++){
          int key = kb*64 + kt*16 + lr;
          float fA = fmaf(sA[kt][r], C1, baseA + sLkt[kt]);
          float fB = fmaf(sB[kt][r], C1, baseB + sLkt[kt]);
          float pA = (key <= qA) ? exp2f(fA) : 0.f;
          float pB = (key <= qB) ? exp2f(fB) : 0.f;
          Psm[w][(g*4+r)*72 + kt*16 + lr]      = f2bf(pA);
          Psm[w][(16 + g*4+r)*72 + kt*16 + lr] = f2bf(pB);
        }
      }
    }
    // O += P V ; lsum += P * ones   (V fragments read once)
    #pragma unroll
    for(int ks=0;ks<2;ks++){
      bf16x8 pfA = ld8(&Psm[w][lr*72 + ks*32 + g*8]);
      bf16x8 pfB = ld8(&Psm[w][(16+lr)*72 + ks*32 + g*8]);
      lsumA = MFMA(pfA, onesb, lsumA);
      lsumB = MFMA(pfB, onesb, lsumB);
      #pragma unroll
      for(int ht=0;ht<4;ht++){
        int row = ht*16 + lr;
        int colp = (ks*32 + g*8) ^ ((row>>3)*8);
        bf16x8 vf = ld8(&Vsm[row*72 + colp]);
        oaccA[ht] = MFMA(pfA, vf, oaccA[ht]);
        oaccB[ht] = MFMA(pfB, vf, oaccB[ht]);
      }
    }
  }
  #pragma unroll
  for(int ht=0;ht<4;ht++){
    #pragma unroll
    for(int r=0;r<4;r++){
      size_t rowA = (size_t)(b*2048 + qb + w*32 + g*4 + r);
      atto[rowA*1024 + h*64 + ht*16 + lr]        = f2bf(oaccA[ht][r] / lsumA[r]);
      atto[(rowA+16)*1024 + h*64 + ht*16 + lr]   = f2bf(oaccB[ht][r] / lsumB[r]);
    }
  }
}

extern "C" void kernel_launch(void* const* d_in, const int* in_sizes, int n_in,
                              void* d_out, int out_size, void* d_ws, size_t ws_size,
                              hipStream_t stream) {
  const float* tok_emb = (const float*)d_in[0];
  const float* ln1_s   = (const float*)d_in[1];
  const float* ln1_b   = (const float*)d_in[2];
  const float* qkv_w   = (const float*)d_in[3];
  const float* qkv_b   = (const float*)d_in[4];
  const float* proj_w  = (const float*)d_in[5];
  const float* proj_b  = (const float*)d_in[6];
  const float* ln2_s   = (const float*)d_in[7];
  const float* ln2_b   = (const float*)d_in[8];
  const float* fc1_w   = (const float*)d_in[9];
  const float* fc1_b   = (const float*)d_in[10];
  const float* fc2_w   = (const float*)d_in[11];
  const float* fc2_b   = (const float*)d_in[12];
  const float* lnf_s   = (const float*)d_in[13];
  const float* lnf_b   = (const float*)d_in[14];
  const int*   idx     = (const int*)d_in[15];

  // scratch plan inside d_out (524 MB, f32 logits written last):
  char* ob = (char*)d_out;
  float* xf32  = (float*)(ob);                                 //  0   .. 16.8 MB
  u16* qkv_bf  = (u16*)(ob + (size_t)16777216);                // 16.8 .. 29.4
  u16* atto_bf = (u16*)(ob + (size_t)29360128);                // 29.4 .. 37.7
  u16* mid_bf  = (u16*)(ob + (size_t)37748736);                // 37.7 .. 71.3
  u16* wt_qkv  = (u16*)(ob + (size_t)71303168);                // 71.3 .. 83.9
  u16* wt_proj = (u16*)(ob + (size_t)83886080);                // 83.9 .. 92.3
  u16* wt_fc1  = (u16*)(ob + (size_t)92274688);                // 92.3 ..125.8
  u16* wt_fc2  = (u16*)(ob + (size_t)125829120);               //125.8 ..159.4
  u16* h_bf    = (u16*)d_ws;                                   //  8.4 MB
  float* out   = (float*)d_out;

  bool big_ws = ws_size >= (size_t)(8388608 + 65536000);
  u16* te_bf = big_ws ? (u16*)((char*)d_ws + 8388608)
                      : (u16*)(ob + (size_t)294912000);

  k_prep<<<36096, 256, 0, stream>>>(tok_emb, te_bf, idx, xf32);
  k_convT<<<dim3(24,16,4), 256, 0, stream>>>(qkv_w,  wt_qkv, 1024, 1536);
  k_convT<<<dim3(16,16,4), 256, 0, stream>>>(proj_w, wt_proj, 1024, 1024);
  k_convT<<<dim3(64,16,4), 256, 0, stream>>>(fc1_w, wt_fc1, 1024, 4096);
  k_convT<<<dim3(16,64,4), 256, 0, stream>>>(fc2_w, wt_fc2, 4096, 1024);

  for(int l=0; l<4; l++){
    k_ln<<<4096, 256, 0, stream>>>(xf32, ln1_s + (size_t)l*1024, ln1_b + (size_t)l*1024, h_bf);
    k_gemm_n64<0><<<dim3(24,32), 256, 0, stream>>>(h_bf, wt_qkv + (size_t)l*1536*1024,
                                                   qkv_b + (size_t)l*1536,
                                                   qkv_bf, nullptr, 4096, 1536, 1024);
    k_attn<<<dim3(16,32), 256, 0, stream>>>(qkv_bf, atto_bf);
    k_gemm_n64<1><<<dim3(16,32), 256, 0, stream>>>(atto_bf, wt_proj + (size_t)l*1024*1024,
                                                   proj_b + (size_t)l*1024,
                                                   nullptr, xf32, 4096, 1024, 1024);
    k_ln<<<4096, 256, 0, stream>>>(xf32, ln2_s + (size_t)l*1024, ln2_b + (size_t)l*1024, h_bf);
    k_gemm<2,0><<<dim3(32,32), 256, 0, stream>>>(h_bf, wt_fc1 + (size_t)l*4096*1024,
                                                 fc1_b + (size_t)l*4096,
                                                 mid_bf, nullptr, 4096, 4096, 1024, 0);
    k_gemm_n64<1><<<dim3(16,32), 256, 0, stream>>>(mid_bf, wt_fc2 + (size_t)l*1024*4096,
                                                   fc2_b + (size_t)l*1024,
                                                   nullptr, xf32, 4096, 1024, 4096);
  }
  k_ln<<<4096, 256, 0, stream>>>(xf32, lnf_s, lnf_b, h_bf);

  if(big_ws){
    k_gemm256<<<dim3(16,125), 512, 0, stream>>>(h_bf, te_bf, out,
                                                4096, 32000, 1024, 0);
  } else {
    k_gemm256<<<dim3(9,125), 512, 0, stream>>>(h_bf, te_bf, out,
                                               4096, 32000, 1024, 0);
    k_gemm256<<<dim3(5,125), 512, 0, stream>>>(h_bf, te_bf, out,
                                               4096, 32000, 1024, 2816);
    k_gemm_f32b<<<dim3(250,4), 256, 0, stream>>>(h_bf, tok_emb, out,
                                                 4096, 32000, 1024, 2304);
  }
}

// Round 21
// 1553.339 us; speedup vs baseline: 1.0111x; 1.0111x over previous
//
#include <hip/hip_runtime.h>

#define DEV __device__ __forceinline__
typedef unsigned short u16;
typedef __bf16 bf16_t;
typedef bf16_t bf16x8 __attribute__((ext_vector_type(8)));
typedef float f32x4 __attribute__((ext_vector_type(4)));

DEV u16 f2bf(float f){ unsigned u=__float_as_uint(f); return (u16)((u + 0x7fffu + ((u>>16)&1u))>>16); }

DEV void gl_lds16(const void* g, void* l){
  __builtin_amdgcn_global_load_lds((__attribute__((address_space(1))) void*)g,
                                   (__attribute__((address_space(3))) void*)l, 16, 0, 0);
}
DEV f32x4 MFMA(bf16x8 a, bf16x8 b, f32x4 c){
  return __builtin_amdgcn_mfma_f32_16x16x32_bf16(a, b, c, 0, 0, 0);
}
DEV bf16x8 ld8(const u16* p){ return *(const bf16x8*)p; }

// ---------------- fused prep: tok_emb f32->bf16 convert + embedding gather
__global__ __launch_bounds__(256) void k_prep(const float* __restrict__ emb,
                                              u16* __restrict__ te,
                                              const int* __restrict__ idx,
                                              float* __restrict__ x){
  int b = blockIdx.x;
  if(b < 32000){
    int i = b*256 + threadIdx.x;          // < 8192000
    float4 v = ((const float4*)emb)[i];
    ushort4 o; o.x=f2bf(v.x); o.y=f2bf(v.y); o.z=f2bf(v.z); o.w=f2bf(v.w);
    ((ushort4*)te)[i] = o;
  } else {
    int row = b - 32000;                  // 0..4095
    int tok = idx[row];
    ((float4*)(x + (size_t)row*1024))[threadIdx.x] =
        ((const float4*)(emb + (size_t)tok*1024))[threadIdx.x];
  }
}

// ---------------- layernorm (fp32 in) -> bf16 out, row = 1024
__global__ __launch_bounds__(256) void k_ln(const float* __restrict__ x,
                                            const float* __restrict__ sc,
                                            const float* __restrict__ bi,
                                            u16* __restrict__ out){
  int row = blockIdx.x;
  const float* xr = x + (size_t)row*1024;
  float4 v = ((const float4*)xr)[threadIdx.x];
  float s = v.x+v.y+v.z+v.w;
  float q = v.x*v.x+v.y*v.y+v.z*v.z+v.w*v.w;
  #pragma unroll
  for(int m=1;m<64;m<<=1){ s += __shfl_xor(s,m); q += __shfl_xor(q,m); }
  __shared__ float ss[4], sq[4];
  int w = threadIdx.x>>6;
  if((threadIdx.x&63)==0){ ss[w]=s; sq[w]=q; }
  __syncthreads();
  s = ss[0]+ss[1]+ss[2]+ss[3];
  q = sq[0]+sq[1]+sq[2]+sq[3];
  float mu = s*(1.f/1024.f);
  float var = q*(1.f/1024.f) - mu*mu;
  float rs = rsqrtf(var + 1e-5f);
  float4 sv = ((const float4*)sc)[threadIdx.x];
  float4 bv = ((const float4*)bi)[threadIdx.x];
  ushort4 o;
  o.x = f2bf((v.x-mu)*rs*sv.x + bv.x);
  o.y = f2bf((v.y-mu)*rs*sv.y + bv.y);
  o.z = f2bf((v.z-mu)*rs*sv.z + bv.z);
  o.w = f2bf((v.w-mu)*rs*sv.w + bv.w);
  *(ushort4*)(out + (size_t)row*1024 + threadIdx.x*4) = o;
}

// ---------------- transpose + convert (64x64, vectorized): W[K][N] f32 -> Wt[N][K] bf16
__global__ __launch_bounds__(256) void k_convT(const float* __restrict__ W,
                                               u16* __restrict__ Wt, int K, int N){
  __shared__ float tile[64][68];
  size_t loff = (size_t)blockIdx.z * K * N;
  W  += loff;  Wt += loff;
  int n0 = blockIdx.x*64, k0 = blockIdx.y*64;
  int tx = threadIdx.x & 15, ty = threadIdx.x >> 4;   // 16 x 16
  #pragma unroll
  for(int r=0;r<4;r++){
    int row = ty + r*16;
    float4 v = *(const float4*)&W[(size_t)(k0+row)*N + n0 + tx*4];
    *(float4*)&tile[row][tx*4] = v;
  }
  __syncthreads();
  int nn = threadIdx.x >> 2, kq = threadIdx.x & 3;
  #pragma unroll
  for(int r=0;r<4;r++){
    int k = (kq + r*4)*4;
    ushort4 o;
    o.x = f2bf(tile[k+0][nn]); o.y = f2bf(tile[k+1][nn]);
    o.z = f2bf(tile[k+2][nn]); o.w = f2bf(tile[k+3][nn]);
    *(ushort4*)&Wt[(size_t)(n0+nn)*K + k0 + k] = o;
  }
}

// ---------------- GEMM 128x128 (2-barrier): C = A * Bt^T, BK=64, XOR swizzle
template<int EPI, int SWAP>
__global__ __launch_bounds__(256) void k_gemm(const u16* __restrict__ A,
                                              const u16* __restrict__ Bt,
                                              const float* __restrict__ bias,
                                              void* __restrict__ out,
                                              float* __restrict__ res,
                                              int M, int N, int K, int m_base){
  __shared__ __align__(16) u16 As[128*64];
  __shared__ __align__(16) u16 Bs[128*64];
  int t = threadIdx.x, l = t & 63, w = t >> 6;
  int g = l >> 4, lr = l & 15;
  int wr = w >> 1, wc = w & 1;
  int m0, n0;
  if constexpr(SWAP){ m0 = m_base + blockIdx.x*128; n0 = blockIdx.y*128; }
  else              { m0 = m_base + blockIdx.y*128; n0 = blockIdx.x*128; }
  f32x4 acc[4][4];
  #pragma unroll
  for(int i=0;i<4;i++)
    #pragma unroll
    for(int j=0;j<4;j++) acc[i][j] = f32x4{0.f,0.f,0.f,0.f};

  int sr = t >> 3;
  int sc = (((t & 7) ^ (sr & 7)) * 8);
  const u16* pa = A  + (size_t)(m0 + sr)*K + sc;
  const u16* pb = Bt + (size_t)(n0 + sr)*K + sc;
  u16* lda = As + t*8;
  u16* ldb = Bs + t*8;
  const int rs_a = (lr & 7)*8;

  for(int k0=0; k0<K; k0+=64){
    #pragma unroll
    for(int i=0;i<4;i++){
      gl_lds16(pa + (size_t)(i*32)*K, lda + i*2048);
      gl_lds16(pb + (size_t)(i*32)*K, ldb + i*2048);
    }
    pa += 64; pb += 64;
    __syncthreads();
    bf16x8 af[4][2], bfr[4][2];
    #pragma unroll
    for(int mi=0;mi<4;mi++){
      int row = wr*64 + mi*16 + lr;
      af[mi][0] = ld8(&As[row*64 + ((g*8     ) ^ rs_a)]);
      af[mi][1] = ld8(&As[row*64 + ((g*8 + 32) ^ rs_a)]);
    }
    #pragma unroll
    for(int ni=0;ni<4;ni++){
      int row = wc*64 + ni*16 + lr;
      bfr[ni][0] = ld8(&Bs[row*64 + ((g*8     ) ^ rs_a)]);
      bfr[ni][1] = ld8(&Bs[row*64 + ((g*8 + 32) ^ rs_a)]);
    }
    #pragma unroll
    for(int mi=0;mi<4;mi++)
      #pragma unroll
      for(int ni=0;ni<4;ni++){
        acc[mi][ni] = MFMA(af[mi][0], bfr[ni][0], acc[mi][ni]);
        acc[mi][ni] = MFMA(af[mi][1], bfr[ni][1], acc[mi][ni]);
      }
    __syncthreads();
  }

  float bv[4];
  #pragma unroll
  for(int ni=0;ni<4;ni++){
    if constexpr(EPI==3) bv[ni] = 0.f;
    else bv[ni] = bias[n0 + wc*64 + ni*16 + lr];
  }
  #pragma unroll
  for(int mi=0;mi<4;mi++){
    int row = m0 + wr*64 + mi*16 + g*4;
    #pragma unroll
    for(int ni=0;ni<4;ni++){
      int col = n0 + wc*64 + ni*16 + lr;
      #pragma unroll
      for(int r=0;r<4;r++){
        float v = acc[mi][ni][r] + bv[ni];
        size_t oidx = (size_t)(row + r)*N + col;
        if constexpr(EPI==0){
          ((u16*)out)[oidx] = f2bf(v);
        } else if constexpr(EPI==1){
          res[oidx] += v;
        } else if constexpr(EPI==2){
          float gv = 0.5f*v*(1.f + erff(v*0.70710678118654752f));
          ((u16*)out)[oidx] = f2bf(gv);
        } else {
          ((float*)out)[oidx] = v;   // f32 logits
        }
      }
    }
  }
}

// ---------------- GEMM 128x64 narrow: high-occupancy even-grid variant
// EPI: 0 = +bias -> bf16 out ; 1 = +bias, res(f32) += v
template<int EPI>
__global__ __launch_bounds__(256) void k_gemm_n64(const u16* __restrict__ A,
                                                  const u16* __restrict__ Bt,
                                                  const float* __restrict__ bias,
                                                  void* __restrict__ outp,
                                                  float* __restrict__ res,
                                                  int M, int N, int K){
  __shared__ __align__(16) u16 As[128*64];
  __shared__ __align__(16) u16 Bs[64*64];
  int t = threadIdx.x, l = t & 63, w = t >> 6;
  int g = l >> 4, lr = l & 15;
  int wr = w >> 1, wc = w & 1;
  int m0 = blockIdx.y*128, n0 = blockIdx.x*64;
  f32x4 acc[4][2];
  #pragma unroll
  for(int i=0;i<4;i++)
    #pragma unroll
    for(int j=0;j<2;j++) acc[i][j] = f32x4{0.f,0.f,0.f,0.f};

  int sr = t >> 3;
  int sc = (((t & 7) ^ (sr & 7)) * 8);
  const u16* pa = A  + (size_t)(m0 + sr)*K + sc;
  const u16* pb = Bt + (size_t)(n0 + sr)*K + sc;
  u16* lda = As + t*8;
  u16* ldb = Bs + t*8;
  const int rs_a = (lr & 7)*8;

  for(int k0=0; k0<K; k0+=64){
    #pragma unroll
    for(int i=0;i<4;i++)
      gl_lds16(pa + (size_t)(i*32)*K, lda + i*2048);
    #pragma unroll
    for(int i=0;i<2;i++)
      gl_lds16(pb + (size_t)(i*32)*K, ldb + i*2048);
    pa += 64; pb += 64;
    __syncthreads();
    bf16x8 af[4][2], bfr[2][2];
    #pragma unroll
    for(int mi=0;mi<4;mi++){
      int row = wr*64 + mi*16 + lr;
      af[mi][0] = ld8(&As[row*64 + ((g*8     ) ^ rs_a)]);
      af[mi][1] = ld8(&As[row*64 + ((g*8 + 32) ^ rs_a)]);
    }
    #pragma unroll
    for(int ni=0;ni<2;ni++){
      int row = wc*32 + ni*16 + lr;
      bfr[ni][0] = ld8(&Bs[row*64 + ((g*8     ) ^ rs_a)]);
      bfr[ni][1] = ld8(&Bs[row*64 + ((g*8 + 32) ^ rs_a)]);
    }
    #pragma unroll
    for(int mi=0;mi<4;mi++)
      #pragma unroll
      for(int ni=0;ni<2;ni++){
        acc[mi][ni] = MFMA(af[mi][0], bfr[ni][0], acc[mi][ni]);
        acc[mi][ni] = MFMA(af[mi][1], bfr[ni][1], acc[mi][ni]);
      }
    __syncthreads();
  }

  float bv[2];
  #pragma unroll
  for(int ni=0;ni<2;ni++) bv[ni] = bias[n0 + wc*32 + ni*16 + lr];
  #pragma unroll
  for(int mi=0;mi<4;mi++){
    int row = m0 + wr*64 + mi*16 + g*4;
    #pragma unroll
    for(int ni=0;ni<2;ni++){
      int col = n0 + wc*32 + ni*16 + lr;
      #pragma unroll
      for(int r=0;r<4;r++){
        float v = acc[mi][ni][r] + bv[ni];
        if constexpr(EPI==0)
          ((u16*)outp)[(size_t)(row + r)*N + col] = f2bf(v);
        else
          res[(size_t)(row + r)*N + col] += v;
      }
    }
  }
}

// ---------------- GEMM 256x256 8-phase (head) — r15 schedule (proven ~350us)
__global__ __launch_bounds__(512) void k_gemm256(const u16* __restrict__ A,
                                                 const u16* __restrict__ Bt,
                                                 float* __restrict__ out,
                                                 int M, int N, int K, int m_base){
  __shared__ __align__(16) u16 As[2][256*64];
  __shared__ __align__(16) u16 Bs[2][256*64];
  int t = threadIdx.x, l = t & 63, wid = t >> 6;
  int g = l >> 4, lr = l & 15;
  int m0 = m_base + blockIdx.x*256, n0 = blockIdx.y*256;
  f32x4 acc[2][16];
  #pragma unroll
  for(int mi=0;mi<2;mi++)
    #pragma unroll
    for(int i=0;i<16;i++) acc[mi][i] = f32x4{0.f,0.f,0.f,0.f};

  int srow = t >> 3;
  int scol = ((t & 7) ^ (srow & 7)) * 8;
  const int rs = (lr & 7) * 8;
  int nt = K >> 6;

  auto stage_half = [&](int jj, int h){
    int buf = jj & 1; int k0s = jj << 6;
    if(h < 2){
      #pragma unroll
      for(int c=0;c<2;c++){
        int rr = h*128 + c*64 + srow;
        gl_lds16(A + (size_t)(m0 + rr)*K + k0s + scol,
                 &As[buf][rr*64 + (t&7)*8]);
      }
    } else {
      #pragma unroll
      for(int c=0;c<2;c++){
        int rr = (h-2)*128 + c*64 + srow;
        gl_lds16(Bt + (size_t)(n0 + rr)*K + k0s + scol,
                 &Bs[buf][rr*64 + (t&7)*8]);
      }
    }
  };

  stage_half(0,0); stage_half(0,1); stage_half(0,2); stage_half(0,3);
  asm volatile("s_waitcnt vmcnt(2)" ::: "memory");
  __builtin_amdgcn_s_barrier();
  __builtin_amdgcn_sched_barrier(0);

  bf16x8 af[2][2];
  for(int j=0; j<nt; ++j){
    const u16* Ab = As[j & 1];
    const u16* Bb = Bs[j & 1];
    bool pf = (j + 1 < nt);
    #pragma unroll
    for(int q=0; q<4; ++q){
      if(q == 0){
        #pragma unroll
        for(int mi=0;mi<2;mi++){
          int row = wid*32 + mi*16 + lr;
          af[mi][0] = ld8(&Ab[row*64 + ((g*8     ) ^ rs)]);
          af[mi][1] = ld8(&Ab[row*64 + ((g*8 + 32) ^ rs)]);
        }
      }
      bf16x8 bfr[4][2];
      #pragma unroll
      for(int i=0;i<4;i++){
        int row = (q*4 + i)*16 + lr;
        bfr[i][0] = ld8(&Bb[row*64 + ((g*8     ) ^ rs)]);
        bfr[i][1] = ld8(&Bb[row*64 + ((g*8 + 32) ^ rs)]);
      }
      if(pf) stage_half(j+1, q);
      __builtin_amdgcn_s_barrier();
      __builtin_amdgcn_sched_barrier(0);
      __builtin_amdgcn_s_setprio(1);
      #pragma unroll
      for(int mi=0;mi<2;mi++)
        #pragma unroll
        for(int i=0;i<4;i++){
          acc[mi][q*4+i] = MFMA(af[mi][0], bfr[i][0], acc[mi][q*4+i]);
          acc[mi][q*4+i] = MFMA(af[mi][1], bfr[i][1], acc[mi][q*4+i]);
        }
      __builtin_amdgcn_s_setprio(0);
      if(q == 1) asm volatile("s_waitcnt vmcnt(4)" ::: "memory");
      if(q == 3) asm volatile("s_waitcnt vmcnt(2)" ::: "memory");
      __builtin_amdgcn_s_barrier();
      __builtin_amdgcn_sched_barrier(0);
    }
  }

  #pragma unroll
  for(int mi=0;mi<2;mi++){
    int row = m0 + wid*32 + mi*16 + g*4;
    #pragma unroll
    for(int i=0;i<16;i++){
      int col = n0 + i*16 + lr;
      #pragma unroll
      for(int r=0;r<4;r++)
        out[(size_t)(row + r)*N + col] = acc[mi][i][r];
    }
  }
}

// ---------------- head GEMM fallback (small-ws only): BK=32 reg-staged B
__global__ __launch_bounds__(256) void k_gemm_f32b(const u16* __restrict__ A,
                                                   const float* __restrict__ B,
                                                   float* __restrict__ out,
                                                   int M, int N, int K, int m_base){
  __shared__ __align__(16) u16 As[128*32];
  __shared__ __align__(16) u16 Bs[128*32];
  int t = threadIdx.x, l = t & 63, w = t >> 6;
  int g = l >> 4, lr = l & 15;
  int wr = w >> 1, wc = w & 1;
  int m0 = m_base + blockIdx.y*128, n0 = blockIdx.x*128;
  f32x4 acc[4][4];
  #pragma unroll
  for(int i=0;i<4;i++)
    #pragma unroll
    for(int j=0;j<4;j++) acc[i][j] = f32x4{0.f,0.f,0.f,0.f};

  int r0 = t >> 2, c0 = (t & 3)*8;
  const u16* pa0 = A + (size_t)(m0 + r0)*K + c0;
  const u16* pa1 = A + (size_t)(m0 + r0 + 64)*K + c0;
  u16* la0 = As + t*8;  u16* la1 = As + (t+256)*8;
  int br = t >> 1, bc = (t & 1)*16;
  const float* pb = B + (size_t)(n0 + br)*K + bc;

  for(int k0=0; k0<K; k0+=32){
    gl_lds16(pa0, la0); gl_lds16(pa1, la1);
    pa0 += 32; pa1 += 32;
    float4 f0 = ((const float4*)pb)[0];
    float4 f1 = ((const float4*)pb)[1];
    float4 f2 = ((const float4*)pb)[2];
    float4 f3 = ((const float4*)pb)[3];
    pb += 32;
    ushort4 u0{f2bf(f0.x),f2bf(f0.y),f2bf(f0.z),f2bf(f0.w)};
    ushort4 u1{f2bf(f1.x),f2bf(f1.y),f2bf(f1.z),f2bf(f1.w)};
    ushort4 u2{f2bf(f2.x),f2bf(f2.y),f2bf(f2.z),f2bf(f2.w)};
    ushort4 u3{f2bf(f3.x),f2bf(f3.y),f2bf(f3.z),f2bf(f3.w)};
    *(ushort4*)&Bs[br*32 + bc +  0] = u0;
    *(ushort4*)&Bs[br*32 + bc +  4] = u1;
    *(ushort4*)&Bs[br*32 + bc +  8] = u2;
    *(ushort4*)&Bs[br*32 + bc + 12] = u3;
    __syncthreads();
    bf16x8 af[4], bfr[4];
    #pragma unroll
    for(int mi=0;mi<4;mi++) af[mi]  = ld8(&As[(wr*64 + mi*16 + lr)*32 + g*8]);
    #pragma unroll
    for(int ni=0;ni<4;ni++) bfr[ni] = ld8(&Bs[(wc*64 + ni*16 + lr)*32 + g*8]);
    #pragma unroll
    for(int mi=0;mi<4;mi++)
      #pragma unroll
      for(int ni=0;ni<4;ni++)
        acc[mi][ni] = MFMA(af[mi], bfr[ni], acc[mi][ni]);
    __syncthreads();
  }

  #pragma unroll
  for(int mi=0;mi<4;mi++){
    int row = m0 + wr*64 + mi*16 + g*4;
    #pragma unroll
    for(int ni=0;ni<4;ni++){
      int col = n0 + wc*64 + ni*16 + lr;
      #pragma unroll
      for(int r=0;r<4;r++)
        out[(size_t)(row + r)*N + col] = acc[mi][ni][r];
    }
  }
}

// ---------------- flash attention, QBLK=128 (8 waves x 16 q-rows), causal+ALiBi
// (r19-verified configuration: interior-tile fast path, fixed-max softmax,
//  MFMA row-sums, XOR-swizzled V)
__global__ __launch_bounds__(512) void k_attn(const u16* __restrict__ qkv,
                                              u16* __restrict__ atto){
  __shared__ __align__(16) u16 Ksm[64*72];
  __shared__ __align__(16) u16 Vsm[64*72];
  __shared__ __align__(16) u16 Psm[8][16*72];
  int t = threadIdx.x, l = t & 63, w = t >> 6, g = l >> 4, lr = l & 15;
  int bh = blockIdx.y; int b = bh >> 4, h = bh & 15, kvh = h >> 2;
  int qb = blockIdx.x * 128;
  const float L2E = 1.44269504088896f;
  const float C1  = 0.125f * L2E;
  float slopeL = exp2f(-0.5f*(float)(h+1)) * L2E;
  float sLkt[4];
  #pragma unroll
  for(int kt=0;kt<4;kt++) sLkt[kt] = slopeL*(float)(kt*16+lr);

  int qrow = qb + w*16 + lr;
  const u16* qp = qkv + (size_t)(b*2048 + qrow)*1536 + h*64;
  bf16x8 qf0 = ld8(qp + g*8);
  bf16x8 qf1 = ld8(qp + 32 + g*8);

  bf16_t onev = (bf16_t)1.0f;
  bf16x8 onesb = {onev,onev,onev,onev,onev,onev,onev,onev};

  f32x4 oacc[4];
  #pragma unroll
  for(int i=0;i<4;i++) oacc[i] = f32x4{0.f,0.f,0.f,0.f};
  f32x4 lsum = f32x4{0.f,0.f,0.f,0.f};

  int qmin_w = qb + w*16;
  int qmax_w = qmin_w + 15;
  int nkb = blockIdx.x*2 + 2;
  for(int kb=0; kb<nkb; kb++){
    __syncthreads();
    {
      int key = t >> 3, ho = (t & 7)*8;
      const u16* src = qkv + (size_t)(b*2048 + kb*64 + key)*1536 + 1024 + kvh*64 + ho;
      *(int4*)&Ksm[key*72 + ho] = *(const int4*)src;
    }
    if(t < 256){
      int key0 = (t>>3)*2, hd0 = (t&7)*8;
      const u16* v0 = qkv + (size_t)(b*2048 + kb*64 + key0)*1536 + 1280 + kvh*64 + hd0;
      int4 A0 = *(const int4*)v0;
      int4 A1 = *(const int4*)(v0 + 1536);
      const u16* ua = (const u16*)&A0; const u16* ub = (const u16*)&A1;
      #pragma unroll
      for(int j=0;j<8;j++){
        int row = hd0 + j;
        int colp = key0 ^ ((row>>3)*8);
        unsigned pr = (unsigned)ua[j] | ((unsigned)ub[j]<<16);
        *(unsigned*)&Vsm[row*72 + colp] = pr;
      }
    }
    __syncthreads();
    if(kb*64 > qmax_w) continue;
    f32x4 sacc[4];
    #pragma unroll
    for(int kt=0;kt<4;kt++) sacc[kt] = f32x4{0.f,0.f,0.f,0.f};
    #pragma unroll
    for(int kt=0;kt<4;kt++){
      bf16x8 kf0 = ld8(&Ksm[(kt*16+lr)*72 + g*8]);
      bf16x8 kf1 = ld8(&Ksm[(kt*16+lr)*72 + 32 + g*8]);
      sacc[kt] = MFMA(qf0, kf0, sacc[kt]);
      sacc[kt] = MFMA(qf1, kf1, sacc[kt]);
    }
    if(kb*64 + 63 <= qmin_w){
      // interior: all keys <= q for every lane -> no mask
      #pragma unroll
      for(int r=0;r<4;r++){
        int q = qb + w*16 + g*4 + r;
        float base = slopeL*(float)(kb*64 - q) - 8.0f*L2E;
        #pragma unroll
        for(int kt=0;kt<4;kt++){
          float f = fmaf(sacc[kt][r], C1, base + sLkt[kt]);
          Psm[w][(g*4+r)*72 + kt*16 + lr] = f2bf(exp2f(f));
        }
      }
    } else {
      #pragma unroll
      for(int r=0;r<4;r++){
        int q = qb + w*16 + g*4 + r;
        float base = slopeL*(float)(kb*64 - q) - 8.0f*L2E;
        #pragma unroll
        for(int kt=0;kt<4;kt++){
          int key = kb*64 + kt*16 + lr;
          float f = fmaf(sacc[kt][r], C1, base + sLkt[kt]);
          float p = (key <= q) ? exp2f(f) : 0.f;
          Psm[w][(g*4+r)*72 + kt*16 + lr] = f2bf(p);
        }
      }
    }
    #pragma unroll
    for(int ks=0;ks<2;ks++){
      bf16x8 pf = ld8(&Psm[w][lr*72 + ks*32 + g*8]);
      lsum = MFMA(pf, onesb, lsum);
      #pragma unroll
      for(int ht=0;ht<4;ht++){
        int row = ht*16 + lr;
        int colp = (ks*32 + g*8) ^ ((row>>3)*8);
        bf16x8 vf = ld8(&Vsm[row*72 + colp]);
        oacc[ht] = MFMA(pf, vf, oacc[ht]);
      }
    }
  }
  #pragma unroll
  for(int ht=0;ht<4;ht++){
    #pragma unroll
    for(int r=0;r<4;r++){
      float o = oacc[ht][r] / lsum[r];
      atto[(size_t)(b*2048 + qb + w*16 + g*4 + r)*1024 + h*64 + ht*16 + lr] = f2bf(o);
    }
  }
}

extern "C" void kernel_launch(void* const* d_in, const int* in_sizes, int n_in,
                              void* d_out, int out_size, void* d_ws, size_t ws_size,
                              hipStream_t stream) {
  const float* tok_emb = (const float*)d_in[0];
  const float* ln1_s   = (const float*)d_in[1];
  const float* ln1_b   = (const float*)d_in[2];
  const float* qkv_w   = (const float*)d_in[3];
  const float* qkv_b   = (const float*)d_in[4];
  const float* proj_w  = (const float*)d_in[5];
  const float* proj_b  = (const float*)d_in[6];
  const float* ln2_s   = (const float*)d_in[7];
  const float* ln2_b   = (const float*)d_in[8];
  const float* fc1_w   = (const float*)d_in[9];
  const float* fc1_b   = (const float*)d_in[10];
  const float* fc2_w   = (const float*)d_in[11];
  const float* fc2_b   = (const float*)d_in[12];
  const float* lnf_s   = (const float*)d_in[13];
  const float* lnf_b   = (const float*)d_in[14];
  const int*   idx     = (const int*)d_in[15];

  // scratch plan inside d_out (524 MB, f32 logits written last):
  char* ob = (char*)d_out;
  float* xf32  = (float*)(ob);                                 //  0   .. 16.8 MB
  u16* qkv_bf  = (u16*)(ob + (size_t)16777216);                // 16.8 .. 29.4
  u16* atto_bf = (u16*)(ob + (size_t)29360128);                // 29.4 .. 37.7
  u16* mid_bf  = (u16*)(ob + (size_t)37748736);                // 37.7 .. 71.3
  u16* wt_qkv  = (u16*)(ob + (size_t)71303168);                // 71.3 .. 83.9
  u16* wt_proj = (u16*)(ob + (size_t)83886080);                // 83.9 .. 92.3
  u16* wt_fc1  = (u16*)(ob + (size_t)92274688);                // 92.3 ..125.8
  u16* wt_fc2  = (u16*)(ob + (size_t)125829120);               //125.8 ..159.4
  u16* h_bf    = (u16*)d_ws;                                   //  8.4 MB
  float* out   = (float*)d_out;

  bool big_ws = ws_size >= (size_t)(8388608 + 65536000);
  u16* te_bf = big_ws ? (u16*)((char*)d_ws + 8388608)
                      : (u16*)(ob + (size_t)294912000);

  k_prep<<<36096, 256, 0, stream>>>(tok_emb, te_bf, idx, xf32);
  k_convT<<<dim3(24,16,4), 256, 0, stream>>>(qkv_w,  wt_qkv, 1024, 1536);
  k_convT<<<dim3(16,16,4), 256, 0, stream>>>(proj_w, wt_proj, 1024, 1024);
  k_convT<<<dim3(64,16,4), 256, 0, stream>>>(fc1_w, wt_fc1, 1024, 4096);
  k_convT<<<dim3(16,64,4), 256, 0, stream>>>(fc2_w, wt_fc2, 4096, 1024);

  for(int l=0; l<4; l++){
    k_ln<<<4096, 256, 0, stream>>>(xf32, ln1_s + (size_t)l*1024, ln1_b + (size_t)l*1024, h_bf);
    k_gemm_n64<0><<<dim3(24,32), 256, 0, stream>>>(h_bf, wt_qkv + (size_t)l*1536*1024,
                                                   qkv_b + (size_t)l*1536,
                                                   qkv_bf, nullptr, 4096, 1536, 1024);
    k_attn<<<dim3(16,32), 512, 0, stream>>>(qkv_bf, atto_bf);
    k_gemm_n64<1><<<dim3(16,32), 256, 0, stream>>>(atto_bf, wt_proj + (size_t)l*1024*1024,
                                                   proj_b + (size_t)l*1024,
                                                   nullptr, xf32, 4096, 1024, 1024);
    k_ln<<<4096, 256, 0, stream>>>(xf32, ln2_s + (size_t)l*1024, ln2_b + (size_t)l*1024, h_bf);
    k_gemm<2,0><<<dim3(32,32), 256, 0, stream>>>(h_bf, wt_fc1 + (size_t)l*4096*1024,
                                                 fc1_b + (size_t)l*4096,
                                                 mid_bf, nullptr, 4096, 4096, 1024, 0);
    k_gemm_n64<1><<<dim3(16,32), 256, 0, stream>>>(mid_bf, wt_fc2 + (size_t)l*1024*4096,
                                                   fc2_b + (size_t)l*1024,
                                                   nullptr, xf32, 4096, 1024, 4096);
  }
  k_ln<<<4096, 256, 0, stream>>>(xf32, lnf_s, lnf_b, h_bf);

  if(big_ws){
    k_gemm256<<<dim3(16,125), 512, 0, stream>>>(h_bf, te_bf, out,
                                                4096, 32000, 1024, 0);
  } else {
    k_gemm256<<<dim3(9,125), 512, 0, stream>>>(h_bf, te_bf, out,
                                               4096, 32000, 1024, 0);
    k_gemm256<<<dim3(5,125), 512, 0, stream>>>(h_bf, te_bf, out,
                                               4096, 32000, 1024, 2816);
    k_gemm_f32b<<<dim3(250,4), 256, 0, stream>>>(h_bf, tok_emb, out,
                                                 4096, 32000, 1024, 2304);
  }
}

// Round 22
// 1526.569 us; speedup vs baseline: 1.0288x; 1.0175x over previous
//
#include <hip/hip_runtime.h>

#define DEV __device__ __forceinline__
typedef unsigned short u16;
typedef __bf16 bf16_t;
typedef bf16_t bf16x8 __attribute__((ext_vector_type(8)));
typedef float f32x4 __attribute__((ext_vector_type(4)));

DEV u16 f2bf(float f){ unsigned u=__float_as_uint(f); return (u16)((u + 0x7fffu + ((u>>16)&1u))>>16); }

DEV void gl_lds16(const void* g, void* l){
  __builtin_amdgcn_global_load_lds((__attribute__((address_space(1))) void*)g,
                                   (__attribute__((address_space(3))) void*)l, 16, 0, 0);
}
DEV f32x4 MFMA(bf16x8 a, bf16x8 b, f32x4 c){
  return __builtin_amdgcn_mfma_f32_16x16x32_bf16(a, b, c, 0, 0, 0);
}
DEV bf16x8 ld8(const u16* p){ return *(const bf16x8*)p; }

// ---------------- fused prep: tok_emb f32->bf16 convert + embedding gather
__global__ __launch_bounds__(256) void k_prep(const float* __restrict__ emb,
                                              u16* __restrict__ te,
                                              const int* __restrict__ idx,
                                              float* __restrict__ x){
  int b = blockIdx.x;
  if(b < 32000){
    int i = b*256 + threadIdx.x;          // < 8192000
    float4 v = ((const float4*)emb)[i];
    ushort4 o; o.x=f2bf(v.x); o.y=f2bf(v.y); o.z=f2bf(v.z); o.w=f2bf(v.w);
    ((ushort4*)te)[i] = o;
  } else {
    int row = b - 32000;                  // 0..4095
    int tok = idx[row];
    ((float4*)(x + (size_t)row*1024))[threadIdx.x] =
        ((const float4*)(emb + (size_t)tok*1024))[threadIdx.x];
  }
}

// ---------------- layernorm (fp32 in) -> bf16 out, row = 1024
__global__ __launch_bounds__(256) void k_ln(const float* __restrict__ x,
                                            const float* __restrict__ sc,
                                            const float* __restrict__ bi,
                                            u16* __restrict__ out){
  int row = blockIdx.x;
  const float* xr = x + (size_t)row*1024;
  float4 v = ((const float4*)xr)[threadIdx.x];
  float s = v.x+v.y+v.z+v.w;
  float q = v.x*v.x+v.y*v.y+v.z*v.z+v.w*v.w;
  #pragma unroll
  for(int m=1;m<64;m<<=1){ s += __shfl_xor(s,m); q += __shfl_xor(q,m); }
  __shared__ float ss[4], sq[4];
  int w = threadIdx.x>>6;
  if((threadIdx.x&63)==0){ ss[w]=s; sq[w]=q; }
  __syncthreads();
  s = ss[0]+ss[1]+ss[2]+ss[3];
  q = sq[0]+sq[1]+sq[2]+sq[3];
  float mu = s*(1.f/1024.f);
  float var = q*(1.f/1024.f) - mu*mu;
  float rs = rsqrtf(var + 1e-5f);
  float4 sv = ((const float4*)sc)[threadIdx.x];
  float4 bv = ((const float4*)bi)[threadIdx.x];
  ushort4 o;
  o.x = f2bf((v.x-mu)*rs*sv.x + bv.x);
  o.y = f2bf((v.y-mu)*rs*sv.y + bv.y);
  o.z = f2bf((v.z-mu)*rs*sv.z + bv.z);
  o.w = f2bf((v.w-mu)*rs*sv.w + bv.w);
  *(ushort4*)(out + (size_t)row*1024 + threadIdx.x*4) = o;
}

// ---------------- transpose + convert (64x64, vectorized): W[K][N] f32 -> Wt[N][K] bf16
__global__ __launch_bounds__(256) void k_convT(const float* __restrict__ W,
                                               u16* __restrict__ Wt, int K, int N){
  __shared__ float tile[64][68];
  size_t loff = (size_t)blockIdx.z * K * N;
  W  += loff;  Wt += loff;
  int n0 = blockIdx.x*64, k0 = blockIdx.y*64;
  int tx = threadIdx.x & 15, ty = threadIdx.x >> 4;   // 16 x 16
  #pragma unroll
  for(int r=0;r<4;r++){
    int row = ty + r*16;
    float4 v = *(const float4*)&W[(size_t)(k0+row)*N + n0 + tx*4];
    *(float4*)&tile[row][tx*4] = v;
  }
  __syncthreads();
  int nn = threadIdx.x >> 2, kq = threadIdx.x & 3;
  #pragma unroll
  for(int r=0;r<4;r++){
    int k = (kq + r*4)*4;
    ushort4 o;
    o.x = f2bf(tile[k+0][nn]); o.y = f2bf(tile[k+1][nn]);
    o.z = f2bf(tile[k+2][nn]); o.w = f2bf(tile[k+3][nn]);
    *(ushort4*)&Wt[(size_t)(n0+nn)*K + k0 + k] = o;
  }
}

// ---------------- GEMM 128x128 (2-barrier): C = A * Bt^T, BK=64, XOR swizzle
template<int EPI, int SWAP>
__global__ __launch_bounds__(256) void k_gemm(const u16* __restrict__ A,
                                              const u16* __restrict__ Bt,
                                              const float* __restrict__ bias,
                                              void* __restrict__ out,
                                              float* __restrict__ res,
                                              int M, int N, int K, int m_base){
  __shared__ __align__(16) u16 As[128*64];
  __shared__ __align__(16) u16 Bs[128*64];
  int t = threadIdx.x, l = t & 63, w = t >> 6;
  int g = l >> 4, lr = l & 15;
  int wr = w >> 1, wc = w & 1;
  int m0, n0;
  if constexpr(SWAP){ m0 = m_base + blockIdx.x*128; n0 = blockIdx.y*128; }
  else              { m0 = m_base + blockIdx.y*128; n0 = blockIdx.x*128; }
  f32x4 acc[4][4];
  #pragma unroll
  for(int i=0;i<4;i++)
    #pragma unroll
    for(int j=0;j<4;j++) acc[i][j] = f32x4{0.f,0.f,0.f,0.f};

  int sr = t >> 3;
  int sc = (((t & 7) ^ (sr & 7)) * 8);
  const u16* pa = A  + (size_t)(m0 + sr)*K + sc;
  const u16* pb = Bt + (size_t)(n0 + sr)*K + sc;
  u16* lda = As + t*8;
  u16* ldb = Bs + t*8;
  const int rs_a = (lr & 7)*8;

  for(int k0=0; k0<K; k0+=64){
    #pragma unroll
    for(int i=0;i<4;i++){
      gl_lds16(pa + (size_t)(i*32)*K, lda + i*2048);
      gl_lds16(pb + (size_t)(i*32)*K, ldb + i*2048);
    }
    pa += 64; pb += 64;
    __syncthreads();
    bf16x8 af[4][2], bfr[4][2];
    #pragma unroll
    for(int mi=0;mi<4;mi++){
      int row = wr*64 + mi*16 + lr;
      af[mi][0] = ld8(&As[row*64 + ((g*8     ) ^ rs_a)]);
      af[mi][1] = ld8(&As[row*64 + ((g*8 + 32) ^ rs_a)]);
    }
    #pragma unroll
    for(int ni=0;ni<4;ni++){
      int row = wc*64 + ni*16 + lr;
      bfr[ni][0] = ld8(&Bs[row*64 + ((g*8     ) ^ rs_a)]);
      bfr[ni][1] = ld8(&Bs[row*64 + ((g*8 + 32) ^ rs_a)]);
    }
    #pragma unroll
    for(int mi=0;mi<4;mi++)
      #pragma unroll
      for(int ni=0;ni<4;ni++){
        acc[mi][ni] = MFMA(af[mi][0], bfr[ni][0], acc[mi][ni]);
        acc[mi][ni] = MFMA(af[mi][1], bfr[ni][1], acc[mi][ni]);
      }
    __syncthreads();
  }

  float bv[4];
  #pragma unroll
  for(int ni=0;ni<4;ni++){
    if constexpr(EPI==3) bv[ni] = 0.f;
    else bv[ni] = bias[n0 + wc*64 + ni*16 + lr];
  }
  #pragma unroll
  for(int mi=0;mi<4;mi++){
    int row = m0 + wr*64 + mi*16 + g*4;
    #pragma unroll
    for(int ni=0;ni<4;ni++){
      int col = n0 + wc*64 + ni*16 + lr;
      #pragma unroll
      for(int r=0;r<4;r++){
        float v = acc[mi][ni][r] + bv[ni];
        size_t oidx = (size_t)(row + r)*N + col;
        if constexpr(EPI==0){
          ((u16*)out)[oidx] = f2bf(v);
        } else if constexpr(EPI==1){
          res[oidx] += v;
        } else if constexpr(EPI==2){
          float gv = 0.5f*v*(1.f + erff(v*0.70710678118654752f));
          ((u16*)out)[oidx] = f2bf(gv);
        } else {
          ((float*)out)[oidx] = v;   // f32 logits
        }
      }
    }
  }
}

// ---------------- GEMM 128x64 narrow: high-occupancy even-grid variant
// EPI: 0 = +bias -> bf16 out ; 1 = +bias, res(f32) += v
template<int EPI>
__global__ __launch_bounds__(256) void k_gemm_n64(const u16* __restrict__ A,
                                                  const u16* __restrict__ Bt,
                                                  const float* __restrict__ bias,
                                                  void* __restrict__ outp,
                                                  float* __restrict__ res,
                                                  int M, int N, int K){
  __shared__ __align__(16) u16 As[128*64];
  __shared__ __align__(16) u16 Bs[64*64];
  int t = threadIdx.x, l = t & 63, w = t >> 6;
  int g = l >> 4, lr = l & 15;
  int wr = w >> 1, wc = w & 1;
  int m0 = blockIdx.y*128, n0 = blockIdx.x*64;
  f32x4 acc[4][2];
  #pragma unroll
  for(int i=0;i<4;i++)
    #pragma unroll
    for(int j=0;j<2;j++) acc[i][j] = f32x4{0.f,0.f,0.f,0.f};

  int sr = t >> 3;
  int sc = (((t & 7) ^ (sr & 7)) * 8);
  const u16* pa = A  + (size_t)(m0 + sr)*K + sc;
  const u16* pb = Bt + (size_t)(n0 + sr)*K + sc;
  u16* lda = As + t*8;
  u16* ldb = Bs + t*8;
  const int rs_a = (lr & 7)*8;

  for(int k0=0; k0<K; k0+=64){
    #pragma unroll
    for(int i=0;i<4;i++)
      gl_lds16(pa + (size_t)(i*32)*K, lda + i*2048);
    #pragma unroll
    for(int i=0;i<2;i++)
      gl_lds16(pb + (size_t)(i*32)*K, ldb + i*2048);
    pa += 64; pb += 64;
    __syncthreads();
    bf16x8 af[4][2], bfr[2][2];
    #pragma unroll
    for(int mi=0;mi<4;mi++){
      int row = wr*64 + mi*16 + lr;
      af[mi][0] = ld8(&As[row*64 + ((g*8     ) ^ rs_a)]);
      af[mi][1] = ld8(&As[row*64 + ((g*8 + 32) ^ rs_a)]);
    }
    #pragma unroll
    for(int ni=0;ni<2;ni++){
      int row = wc*32 + ni*16 + lr;
      bfr[ni][0] = ld8(&Bs[row*64 + ((g*8     ) ^ rs_a)]);
      bfr[ni][1] = ld8(&Bs[row*64 + ((g*8 + 32) ^ rs_a)]);
    }
    #pragma unroll
    for(int mi=0;mi<4;mi++)
      #pragma unroll
      for(int ni=0;ni<2;ni++){
        acc[mi][ni] = MFMA(af[mi][0], bfr[ni][0], acc[mi][ni]);
        acc[mi][ni] = MFMA(af[mi][1], bfr[ni][1], acc[mi][ni]);
      }
    __syncthreads();
  }

  float bv[2];
  #pragma unroll
  for(int ni=0;ni<2;ni++) bv[ni] = bias[n0 + wc*32 + ni*16 + lr];
  #pragma unroll
  for(int mi=0;mi<4;mi++){
    int row = m0 + wr*64 + mi*16 + g*4;
    #pragma unroll
    for(int ni=0;ni<2;ni++){
      int col = n0 + wc*32 + ni*16 + lr;
      #pragma unroll
      for(int r=0;r<4;r++){
        float v = acc[mi][ni][r] + bv[ni];
        if constexpr(EPI==0)
          ((u16*)outp)[(size_t)(row + r)*N + col] = f2bf(v);
        else
          res[(size_t)(row + r)*N + col] += v;
      }
    }
  }
}

// ---------------- GEMM 256x256 8-phase (head) — r15 schedule (proven ~350us)
__global__ __launch_bounds__(512) void k_gemm256(const u16* __restrict__ A,
                                                 const u16* __restrict__ Bt,
                                                 float* __restrict__ out,
                                                 int M, int N, int K, int m_base){
  __shared__ __align__(16) u16 As[2][256*64];
  __shared__ __align__(16) u16 Bs[2][256*64];
  int t = threadIdx.x, l = t & 63, wid = t >> 6;
  int g = l >> 4, lr = l & 15;
  int m0 = m_base + blockIdx.x*256, n0 = blockIdx.y*256;
  f32x4 acc[2][16];
  #pragma unroll
  for(int mi=0;mi<2;mi++)
    #pragma unroll
    for(int i=0;i<16;i++) acc[mi][i] = f32x4{0.f,0.f,0.f,0.f};

  int srow = t >> 3;
  int scol = ((t & 7) ^ (srow & 7)) * 8;
  const int rs = (lr & 7) * 8;
  int nt = K >> 6;

  auto stage_half = [&](int jj, int h){
    int buf = jj & 1; int k0s = jj << 6;
    if(h < 2){
      #pragma unroll
      for(int c=0;c<2;c++){
        int rr = h*128 + c*64 + srow;
        gl_lds16(A + (size_t)(m0 + rr)*K + k0s + scol,
                 &As[buf][rr*64 + (t&7)*8]);
      }
    } else {
      #pragma unroll
      for(int c=0;c<2;c++){
        int rr = (h-2)*128 + c*64 + srow;
        gl_lds16(Bt + (size_t)(n0 + rr)*K + k0s + scol,
                 &Bs[buf][rr*64 + (t&7)*8]);
      }
    }
  };

  stage_half(0,0); stage_half(0,1); stage_half(0,2); stage_half(0,3);
  asm volatile("s_waitcnt vmcnt(2)" ::: "memory");
  __builtin_amdgcn_s_barrier();
  __builtin_amdgcn_sched_barrier(0);

  bf16x8 af[2][2];
  for(int j=0; j<nt; ++j){
    const u16* Ab = As[j & 1];
    const u16* Bb = Bs[j & 1];
    bool pf = (j + 1 < nt);
    #pragma unroll
    for(int q=0; q<4; ++q){
      if(q == 0){
        #pragma unroll
        for(int mi=0;mi<2;mi++){
          int row = wid*32 + mi*16 + lr;
          af[mi][0] = ld8(&Ab[row*64 + ((g*8     ) ^ rs)]);
          af[mi][1] = ld8(&Ab[row*64 + ((g*8 + 32) ^ rs)]);
        }
      }
      bf16x8 bfr[4][2];
      #pragma unroll
      for(int i=0;i<4;i++){
        int row = (q*4 + i)*16 + lr;
        bfr[i][0] = ld8(&Bb[row*64 + ((g*8     ) ^ rs)]);
        bfr[i][1] = ld8(&Bb[row*64 + ((g*8 + 32) ^ rs)]);
      }
      if(pf) stage_half(j+1, q);
      __builtin_amdgcn_s_barrier();
      __builtin_amdgcn_sched_barrier(0);
      __builtin_amdgcn_s_setprio(1);
      #pragma unroll
      for(int mi=0;mi<2;mi++)
        #pragma unroll
        for(int i=0;i<4;i++){
          acc[mi][q*4+i] = MFMA(af[mi][0], bfr[i][0], acc[mi][q*4+i]);
          acc[mi][q*4+i] = MFMA(af[mi][1], bfr[i][1], acc[mi][q*4+i]);
        }
      __builtin_amdgcn_s_setprio(0);
      if(q == 1) asm volatile("s_waitcnt vmcnt(4)" ::: "memory");
      if(q == 3) asm volatile("s_waitcnt vmcnt(2)" ::: "memory");
      __builtin_amdgcn_s_barrier();
      __builtin_amdgcn_sched_barrier(0);
    }
  }

  #pragma unroll
  for(int mi=0;mi<2;mi++){
    int row = m0 + wid*32 + mi*16 + g*4;
    #pragma unroll
    for(int i=0;i<16;i++){
      int col = n0 + i*16 + lr;
      #pragma unroll
      for(int r=0;r<4;r++)
        out[(size_t)(row + r)*N + col] = acc[mi][i][r];
    }
  }
}

// ---------------- head GEMM fallback (small-ws only): BK=32 reg-staged B
__global__ __launch_bounds__(256) void k_gemm_f32b(const u16* __restrict__ A,
                                                   const float* __restrict__ B,
                                                   float* __restrict__ out,
                                                   int M, int N, int K, int m_base){
  __shared__ __align__(16) u16 As[128*32];
  __shared__ __align__(16) u16 Bs[128*32];
  int t = threadIdx.x, l = t & 63, w = t >> 6;
  int g = l >> 4, lr = l & 15;
  int wr = w >> 1, wc = w & 1;
  int m0 = m_base + blockIdx.y*128, n0 = blockIdx.x*128;
  f32x4 acc[4][4];
  #pragma unroll
  for(int i=0;i<4;i++)
    #pragma unroll
    for(int j=0;j<4;j++) acc[i][j] = f32x4{0.f,0.f,0.f,0.f};

  int r0 = t >> 2, c0 = (t & 3)*8;
  const u16* pa0 = A + (size_t)(m0 + r0)*K + c0;
  const u16* pa1 = A + (size_t)(m0 + r0 + 64)*K + c0;
  u16* la0 = As + t*8;  u16* la1 = As + (t+256)*8;
  int br = t >> 1, bc = (t & 1)*16;
  const float* pb = B + (size_t)(n0 + br)*K + bc;

  for(int k0=0; k0<K; k0+=32){
    gl_lds16(pa0, la0); gl_lds16(pa1, la1);
    pa0 += 32; pa1 += 32;
    float4 f0 = ((const float4*)pb)[0];
    float4 f1 = ((const float4*)pb)[1];
    float4 f2 = ((const float4*)pb)[2];
    float4 f3 = ((const float4*)pb)[3];
    pb += 32;
    ushort4 u0{f2bf(f0.x),f2bf(f0.y),f2bf(f0.z),f2bf(f0.w)};
    ushort4 u1{f2bf(f1.x),f2bf(f1.y),f2bf(f1.z),f2bf(f1.w)};
    ushort4 u2{f2bf(f2.x),f2bf(f2.y),f2bf(f2.z),f2bf(f2.w)};
    ushort4 u3{f2bf(f3.x),f2bf(f3.y),f2bf(f3.z),f2bf(f3.w)};
    *(ushort4*)&Bs[br*32 + bc +  0] = u0;
    *(ushort4*)&Bs[br*32 + bc +  4] = u1;
    *(ushort4*)&Bs[br*32 + bc +  8] = u2;
    *(ushort4*)&Bs[br*32 + bc + 12] = u3;
    __syncthreads();
    bf16x8 af[4], bfr[4];
    #pragma unroll
    for(int mi=0;mi<4;mi++) af[mi]  = ld8(&As[(wr*64 + mi*16 + lr)*32 + g*8]);
    #pragma unroll
    for(int ni=0;ni<4;ni++) bfr[ni] = ld8(&Bs[(wc*64 + ni*16 + lr)*32 + g*8]);
    #pragma unroll
    for(int mi=0;mi<4;mi++)
      #pragma unroll
      for(int ni=0;ni<4;ni++)
        acc[mi][ni] = MFMA(af[mi], bfr[ni], acc[mi][ni]);
    __syncthreads();
  }

  #pragma unroll
  for(int mi=0;mi<4;mi++){
    int row = m0 + wr*64 + mi*16 + g*4;
    #pragma unroll
    for(int ni=0;ni<4;ni++){
      int col = n0 + wc*64 + ni*16 + lr;
      #pragma unroll
      for(int r=0;r<4;r++)
        out[(size_t)(row + r)*N + col] = acc[mi][ni][r];
    }
  }
}

// ---------------- flash attention, QBLK=128 (8 waves x 16 q-rows), causal+ALiBi
// T14 async-STAGE split: issue K/V global loads for tile kb+1 into registers
// right after tile kb's LDS-ready barrier (overlaps kb's compute); write
// registers -> LDS after the next reads-done barrier. Same bytes/math as r21.
__global__ __launch_bounds__(512) void k_attn(const u16* __restrict__ qkv,
                                              u16* __restrict__ atto){
  __shared__ __align__(16) u16 Ksm[64*72];
  __shared__ __align__(16) u16 Vsm[64*72];
  __shared__ __align__(16) u16 Psm[8][16*72];
  int t = threadIdx.x, l = t & 63, w = t >> 6, g = l >> 4, lr = l & 15;
  int bh = blockIdx.y; int b = bh >> 4, h = bh & 15, kvh = h >> 2;
  int qb = blockIdx.x * 128;
  const float L2E = 1.44269504088896f;
  const float C1  = 0.125f * L2E;
  float slopeL = exp2f(-0.5f*(float)(h+1)) * L2E;
  float sLkt[4];
  #pragma unroll
  for(int kt=0;kt<4;kt++) sLkt[kt] = slopeL*(float)(kt*16+lr);

  int qrow = qb + w*16 + lr;
  const u16* qp = qkv + (size_t)(b*2048 + qrow)*1536 + h*64;
  bf16x8 qf0 = ld8(qp + g*8);
  bf16x8 qf1 = ld8(qp + 32 + g*8);

  bf16_t onev = (bf16_t)1.0f;
  bf16x8 onesb = {onev,onev,onev,onev,onev,onev,onev,onev};

  f32x4 oacc[4];
  #pragma unroll
  for(int i=0;i<4;i++) oacc[i] = f32x4{0.f,0.f,0.f,0.f};
  f32x4 lsum = f32x4{0.f,0.f,0.f,0.f};

  // staging addresses (fixed per thread)
  int skey = t >> 3, sho = (t & 7)*8;                 // K: 1 int4/thread
  int vkey0 = (t>>3)*2, vhd0 = (t&7)*8;               // V: 2 int4 (t<256)
  int4 kreg, vreg0, vreg1;
  auto issue = [&](int kb){
    kreg = *(const int4*)(qkv + (size_t)(b*2048 + kb*64 + skey)*1536 + 1024 + kvh*64 + sho);
    if(t < 256){
      const u16* v0 = qkv + (size_t)(b*2048 + kb*64 + vkey0)*1536 + 1280 + kvh*64 + vhd0;
      vreg0 = *(const int4*)v0;
      vreg1 = *(const int4*)(v0 + 1536);
    }
  };

  int qmin_w = qb + w*16;
  int qmax_w = qmin_w + 15;
  int nkb = blockIdx.x*2 + 2;
  issue(0);
  for(int kb=0; kb<nkb; kb++){
    __syncthreads();                  // prior tile's LDS reads complete
    // write staged registers -> LDS
    *(int4*)&Ksm[skey*72 + sho] = kreg;
    if(t < 256){
      const u16* ua = (const u16*)&vreg0; const u16* ub = (const u16*)&vreg1;
      #pragma unroll
      for(int j=0;j<8;j++){
        int row = vhd0 + j;
        int colp = vkey0 ^ ((row>>3)*8);
        unsigned pr = (unsigned)ua[j] | ((unsigned)ub[j]<<16);
        *(unsigned*)&Vsm[row*72 + colp] = pr;
      }
    }
    __syncthreads();                  // tile kb ready
    if(kb + 1 < nkb) issue(kb + 1);   // overlap next loads with compute
    if(kb*64 > qmax_w) continue;
    f32x4 sacc[4];
    #pragma unroll
    for(int kt=0;kt<4;kt++) sacc[kt] = f32x4{0.f,0.f,0.f,0.f};
    #pragma unroll
    for(int kt=0;kt<4;kt++){
      bf16x8 kf0 = ld8(&Ksm[(kt*16+lr)*72 + g*8]);
      bf16x8 kf1 = ld8(&Ksm[(kt*16+lr)*72 + 32 + g*8]);
      sacc[kt] = MFMA(qf0, kf0, sacc[kt]);
      sacc[kt] = MFMA(qf1, kf1, sacc[kt]);
    }
    if(kb*64 + 63 <= qmin_w){
      // interior: all keys <= q for every lane -> no mask
      #pragma unroll
      for(int r=0;r<4;r++){
        int q = qb + w*16 + g*4 + r;
        float base = slopeL*(float)(kb*64 - q) - 8.0f*L2E;
        #pragma unroll
        for(int kt=0;kt<4;kt++){
          float f = fmaf(sacc[kt][r], C1, base + sLkt[kt]);
          Psm[w][(g*4+r)*72 + kt*16 + lr] = f2bf(exp2f(f));
        }
      }
    } else {
      #pragma unroll
      for(int r=0;r<4;r++){
        int q = qb + w*16 + g*4 + r;
        float base = slopeL*(float)(kb*64 - q) - 8.0f*L2E;
        #pragma unroll
        for(int kt=0;kt<4;kt++){
          int key = kb*64 + kt*16 + lr;
          float f = fmaf(sacc[kt][r], C1, base + sLkt[kt]);
          float p = (key <= q) ? exp2f(f) : 0.f;
          Psm[w][(g*4+r)*72 + kt*16 + lr] = f2bf(p);
        }
      }
    }
    #pragma unroll
    for(int ks=0;ks<2;ks++){
      bf16x8 pf = ld8(&Psm[w][lr*72 + ks*32 + g*8]);
      lsum = MFMA(pf, onesb, lsum);
      #pragma unroll
      for(int ht=0;ht<4;ht++){
        int row = ht*16 + lr;
        int colp = (ks*32 + g*8) ^ ((row>>3)*8);
        bf16x8 vf = ld8(&Vsm[row*72 + colp]);
        oacc[ht] = MFMA(pf, vf, oacc[ht]);
      }
    }
  }
  #pragma unroll
  for(int ht=0;ht<4;ht++){
    #pragma unroll
    for(int r=0;r<4;r++){
      float o = oacc[ht][r] / lsum[r];
      atto[(size_t)(b*2048 + qb + w*16 + g*4 + r)*1024 + h*64 + ht*16 + lr] = f2bf(o);
    }
  }
}

extern "C" void kernel_launch(void* const* d_in, const int* in_sizes, int n_in,
                              void* d_out, int out_size, void* d_ws, size_t ws_size,
                              hipStream_t stream) {
  const float* tok_emb = (const float*)d_in[0];
  const float* ln1_s   = (const float*)d_in[1];
  const float* ln1_b   = (const float*)d_in[2];
  const float* qkv_w   = (const float*)d_in[3];
  const float* qkv_b   = (const float*)d_in[4];
  const float* proj_w  = (const float*)d_in[5];
  const float* proj_b  = (const float*)d_in[6];
  const float* ln2_s   = (const float*)d_in[7];
  const float* ln2_b   = (const float*)d_in[8];
  const float* fc1_w   = (const float*)d_in[9];
  const float* fc1_b   = (const float*)d_in[10];
  const float* fc2_w   = (const float*)d_in[11];
  const float* fc2_b   = (const float*)d_in[12];
  const float* lnf_s   = (const float*)d_in[13];
  const float* lnf_b   = (const float*)d_in[14];
  const int*   idx     = (const int*)d_in[15];

  // scratch plan inside d_out (524 MB, f32 logits written last):
  char* ob = (char*)d_out;
  float* xf32  = (float*)(ob);                                 //  0   .. 16.8 MB
  u16* qkv_bf  = (u16*)(ob + (size_t)16777216);                // 16.8 .. 29.4
  u16* atto_bf = (u16*)(ob + (size_t)29360128);                // 29.4 .. 37.7
  u16* mid_bf  = (u16*)(ob + (size_t)37748736);                // 37.7 .. 71.3
  u16* wt_qkv  = (u16*)(ob + (size_t)71303168);                // 71.3 .. 83.9
  u16* wt_proj = (u16*)(ob + (size_t)83886080);                // 83.9 .. 92.3
  u16* wt_fc1  = (u16*)(ob + (size_t)92274688);                // 92.3 ..125.8
  u16* wt_fc2  = (u16*)(ob + (size_t)125829120);               //125.8 ..159.4
  u16* h_bf    = (u16*)d_ws;                                   //  8.4 MB
  float* out   = (float*)d_out;

  bool big_ws = ws_size >= (size_t)(8388608 + 65536000);
  u16* te_bf = big_ws ? (u16*)((char*)d_ws + 8388608)
                      : (u16*)(ob + (size_t)294912000);

  k_prep<<<36096, 256, 0, stream>>>(tok_emb, te_bf, idx, xf32);
  k_convT<<<dim3(24,16,4), 256, 0, stream>>>(qkv_w,  wt_qkv, 1024, 1536);
  k_convT<<<dim3(16,16,4), 256, 0, stream>>>(proj_w, wt_proj, 1024, 1024);
  k_convT<<<dim3(64,16,4), 256, 0, stream>>>(fc1_w, wt_fc1, 1024, 4096);
  k_convT<<<dim3(16,64,4), 256, 0, stream>>>(fc2_w, wt_fc2, 4096, 1024);

  for(int l=0; l<4; l++){
    k_ln<<<4096, 256, 0, stream>>>(xf32, ln1_s + (size_t)l*1024, ln1_b + (size_t)l*1024, h_bf);
    k_gemm_n64<0><<<dim3(24,32), 256, 0, stream>>>(h_bf, wt_qkv + (size_t)l*1536*1024,
                                                   qkv_b + (size_t)l*1536,
                                                   qkv_bf, nullptr, 4096, 1536, 1024);
    k_attn<<<dim3(16,32), 512, 0, stream>>>(qkv_bf, atto_bf);
    k_gemm_n64<1><<<dim3(16,32), 256, 0, stream>>>(atto_bf, wt_proj + (size_t)l*1024*1024,
                                                   proj_b + (size_t)l*1024,
                                                   nullptr, xf32, 4096, 1024, 1024);
    k_ln<<<4096, 256, 0, stream>>>(xf32, ln2_s + (size_t)l*1024, ln2_b + (size_t)l*1024, h_bf);
    k_gemm<2,0><<<dim3(32,32), 256, 0, stream>>>(h_bf, wt_fc1 + (size_t)l*4096*1024,
                                                 fc1_b + (size_t)l*4096,
                                                 mid_bf, nullptr, 4096, 4096, 1024, 0);
    k_gemm_n64<1><<<dim3(16,32), 256, 0, stream>>>(mid_bf, wt_fc2 + (size_t)l*1024*4096,
                                                   fc2_b + (size_t)l*1024,
                                                   nullptr, xf32, 4096, 1024, 4096);
  }
  k_ln<<<4096, 256, 0, stream>>>(xf32, lnf_s, lnf_b, h_bf);

  if(big_ws){
    k_gemm256<<<dim3(16,125), 512, 0, stream>>>(h_bf, te_bf, out,
                                                4096, 32000, 1024, 0);
  } else {
    k_gemm256<<<dim3(9,125), 512, 0, stream>>>(h_bf, te_bf, out,
                                               4096, 32000, 1024, 0);
    k_gemm256<<<dim3(5,125), 512, 0, stream>>>(h_bf, te_bf, out,
                                               4096, 32000, 1024, 2816);
    k_gemm_f32b<<<dim3(250,4), 256, 0, stream>>>(h_bf, tok_emb, out,
                                                 4096, 32000, 1024, 2304);
  }
}

// Round 23
// 1456.861 us; speedup vs baseline: 1.0780x; 1.0478x over previous
//
#include <hip/hip_runtime.h>

#define DEV __device__ __forceinline__
typedef unsigned short u16;
typedef __bf16 bf16_t;
typedef bf16_t bf16x8 __attribute__((ext_vector_type(8)));
typedef float f32x4 __attribute__((ext_vector_type(4)));

DEV u16 f2bf(float f){ unsigned u=__float_as_uint(f); return (u16)((u + 0x7fffu + ((u>>16)&1u))>>16); }

DEV void gl_lds16(const void* g, void* l){
  __builtin_amdgcn_global_load_lds((__attribute__((address_space(1))) void*)g,
                                   (__attribute__((address_space(3))) void*)l, 16, 0, 0);
}
DEV f32x4 MFMA(bf16x8 a, bf16x8 b, f32x4 c){
  return __builtin_amdgcn_mfma_f32_16x16x32_bf16(a, b, c, 0, 0, 0);
}
DEV bf16x8 ld8(const u16* p){ return *(const bf16x8*)p; }

// ---------------- fused prep: tok_emb f32->bf16 convert + embedding gather
__global__ __launch_bounds__(256) void k_prep(const float* __restrict__ emb,
                                              u16* __restrict__ te,
                                              const int* __restrict__ idx,
                                              float* __restrict__ x){
  int b = blockIdx.x;
  if(b < 32000){
    int i = b*256 + threadIdx.x;          // < 8192000
    float4 v = ((const float4*)emb)[i];
    ushort4 o; o.x=f2bf(v.x); o.y=f2bf(v.y); o.z=f2bf(v.z); o.w=f2bf(v.w);
    ((ushort4*)te)[i] = o;
  } else {
    int row = b - 32000;                  // 0..4095
    int tok = idx[row];
    ((float4*)(x + (size_t)row*1024))[threadIdx.x] =
        ((const float4*)(emb + (size_t)tok*1024))[threadIdx.x];
  }
}

// ---------------- layernorm (fp32 in) -> bf16 out, row = 1024
__global__ __launch_bounds__(256) void k_ln(const float* __restrict__ x,
                                            const float* __restrict__ sc,
                                            const float* __restrict__ bi,
                                            u16* __restrict__ out){
  int row = blockIdx.x;
  const float* xr = x + (size_t)row*1024;
  float4 v = ((const float4*)xr)[threadIdx.x];
  float s = v.x+v.y+v.z+v.w;
  float q = v.x*v.x+v.y*v.y+v.z*v.z+v.w*v.w;
  #pragma unroll
  for(int m=1;m<64;m<<=1){ s += __shfl_xor(s,m); q += __shfl_xor(q,m); }
  __shared__ float ss[4], sq[4];
  int w = threadIdx.x>>6;
  if((threadIdx.x&63)==0){ ss[w]=s; sq[w]=q; }
  __syncthreads();
  s = ss[0]+ss[1]+ss[2]+ss[3];
  q = sq[0]+sq[1]+sq[2]+sq[3];
  float mu = s*(1.f/1024.f);
  float var = q*(1.f/1024.f) - mu*mu;
  float rs = rsqrtf(var + 1e-5f);
  float4 sv = ((const float4*)sc)[threadIdx.x];
  float4 bv = ((const float4*)bi)[threadIdx.x];
  ushort4 o;
  o.x = f2bf((v.x-mu)*rs*sv.x + bv.x);
  o.y = f2bf((v.y-mu)*rs*sv.y + bv.y);
  o.z = f2bf((v.z-mu)*rs*sv.z + bv.z);
  o.w = f2bf((v.w-mu)*rs*sv.w + bv.w);
  *(ushort4*)(out + (size_t)row*1024 + threadIdx.x*4) = o;
}

// ---------------- transpose + convert (64x64, vectorized): W[K][N] f32 -> Wt[N][K] bf16
__global__ __launch_bounds__(256) void k_convT(const float* __restrict__ W,
                                               u16* __restrict__ Wt, int K, int N){
  __shared__ float tile[64][68];
  size_t loff = (size_t)blockIdx.z * K * N;
  W  += loff;  Wt += loff;
  int n0 = blockIdx.x*64, k0 = blockIdx.y*64;
  int tx = threadIdx.x & 15, ty = threadIdx.x >> 4;   // 16 x 16
  #pragma unroll
  for(int r=0;r<4;r++){
    int row = ty + r*16;
    float4 v = *(const float4*)&W[(size_t)(k0+row)*N + n0 + tx*4];
    *(float4*)&tile[row][tx*4] = v;
  }
  __syncthreads();
  int nn = threadIdx.x >> 2, kq = threadIdx.x & 3;
  #pragma unroll
  for(int r=0;r<4;r++){
    int k = (kq + r*4)*4;
    ushort4 o;
    o.x = f2bf(tile[k+0][nn]); o.y = f2bf(tile[k+1][nn]);
    o.z = f2bf(tile[k+2][nn]); o.w = f2bf(tile[k+3][nn]);
    *(ushort4*)&Wt[(size_t)(n0+nn)*K + k0 + k] = o;
  }
}

// ---------------- GEMM 128x128 (2-barrier): C = A * Bt^T, BK=64, XOR swizzle
template<int EPI, int SWAP>
__global__ __launch_bounds__(256) void k_gemm(const u16* __restrict__ A,
                                              const u16* __restrict__ Bt,
                                              const float* __restrict__ bias,
                                              void* __restrict__ out,
                                              float* __restrict__ res,
                                              int M, int N, int K, int m_base){
  __shared__ __align__(16) u16 As[128*64];
  __shared__ __align__(16) u16 Bs[128*64];
  int t = threadIdx.x, l = t & 63, w = t >> 6;
  int g = l >> 4, lr = l & 15;
  int wr = w >> 1, wc = w & 1;
  int m0, n0;
  if constexpr(SWAP){ m0 = m_base + blockIdx.x*128; n0 = blockIdx.y*128; }
  else              { m0 = m_base + blockIdx.y*128; n0 = blockIdx.x*128; }
  f32x4 acc[4][4];
  #pragma unroll
  for(int i=0;i<4;i++)
    #pragma unroll
    for(int j=0;j<4;j++) acc[i][j] = f32x4{0.f,0.f,0.f,0.f};

  int sr = t >> 3;
  int sc = (((t & 7) ^ (sr & 7)) * 8);
  const u16* pa = A  + (size_t)(m0 + sr)*K + sc;
  const u16* pb = Bt + (size_t)(n0 + sr)*K + sc;
  u16* lda = As + t*8;
  u16* ldb = Bs + t*8;
  const int rs_a = (lr & 7)*8;

  for(int k0=0; k0<K; k0+=64){
    #pragma unroll
    for(int i=0;i<4;i++){
      gl_lds16(pa + (size_t)(i*32)*K, lda + i*2048);
      gl_lds16(pb + (size_t)(i*32)*K, ldb + i*2048);
    }
    pa += 64; pb += 64;
    __syncthreads();
    bf16x8 af[4][2], bfr[4][2];
    #pragma unroll
    for(int mi=0;mi<4;mi++){
      int row = wr*64 + mi*16 + lr;
      af[mi][0] = ld8(&As[row*64 + ((g*8     ) ^ rs_a)]);
      af[mi][1] = ld8(&As[row*64 + ((g*8 + 32) ^ rs_a)]);
    }
    #pragma unroll
    for(int ni=0;ni<4;ni++){
      int row = wc*64 + ni*16 + lr;
      bfr[ni][0] = ld8(&Bs[row*64 + ((g*8     ) ^ rs_a)]);
      bfr[ni][1] = ld8(&Bs[row*64 + ((g*8 + 32) ^ rs_a)]);
    }
    #pragma unroll
    for(int mi=0;mi<4;mi++)
      #pragma unroll
      for(int ni=0;ni<4;ni++){
        acc[mi][ni] = MFMA(af[mi][0], bfr[ni][0], acc[mi][ni]);
        acc[mi][ni] = MFMA(af[mi][1], bfr[ni][1], acc[mi][ni]);
      }
    __syncthreads();
  }

  float bv[4];
  #pragma unroll
  for(int ni=0;ni<4;ni++){
    if constexpr(EPI==3) bv[ni] = 0.f;
    else bv[ni] = bias[n0 + wc*64 + ni*16 + lr];
  }
  #pragma unroll
  for(int mi=0;mi<4;mi++){
    int row = m0 + wr*64 + mi*16 + g*4;
    #pragma unroll
    for(int ni=0;ni<4;ni++){
      int col = n0 + wc*64 + ni*16 + lr;
      #pragma unroll
      for(int r=0;r<4;r++){
        float v = acc[mi][ni][r] + bv[ni];
        size_t oidx = (size_t)(row + r)*N + col;
        if constexpr(EPI==0){
          ((u16*)out)[oidx] = f2bf(v);
        } else if constexpr(EPI==1){
          res[oidx] += v;
        } else if constexpr(EPI==2){
          float gv = 0.5f*v*(1.f + erff(v*0.70710678118654752f));
          ((u16*)out)[oidx] = f2bf(gv);
        } else {
          ((float*)out)[oidx] = v;   // f32 logits
        }
      }
    }
  }
}

// ---------------- GEMM 128x64 narrow: high-occupancy even-grid variant
// EPI: 0 = +bias -> bf16 out ; 1 = +bias, res(f32) += v
template<int EPI>
__global__ __launch_bounds__(256) void k_gemm_n64(const u16* __restrict__ A,
                                                  const u16* __restrict__ Bt,
                                                  const float* __restrict__ bias,
                                                  void* __restrict__ outp,
                                                  float* __restrict__ res,
                                                  int M, int N, int K){
  __shared__ __align__(16) u16 As[128*64];
  __shared__ __align__(16) u16 Bs[64*64];
  int t = threadIdx.x, l = t & 63, w = t >> 6;
  int g = l >> 4, lr = l & 15;
  int wr = w >> 1, wc = w & 1;
  int m0 = blockIdx.y*128, n0 = blockIdx.x*64;
  f32x4 acc[4][2];
  #pragma unroll
  for(int i=0;i<4;i++)
    #pragma unroll
    for(int j=0;j<2;j++) acc[i][j] = f32x4{0.f,0.f,0.f,0.f};

  int sr = t >> 3;
  int sc = (((t & 7) ^ (sr & 7)) * 8);
  const u16* pa = A  + (size_t)(m0 + sr)*K + sc;
  const u16* pb = Bt + (size_t)(n0 + sr)*K + sc;
  u16* lda = As + t*8;
  u16* ldb = Bs + t*8;
  const int rs_a = (lr & 7)*8;

  for(int k0=0; k0<K; k0+=64){
    #pragma unroll
    for(int i=0;i<4;i++)
      gl_lds16(pa + (size_t)(i*32)*K, lda + i*2048);
    #pragma unroll
    for(int i=0;i<2;i++)
      gl_lds16(pb + (size_t)(i*32)*K, ldb + i*2048);
    pa += 64; pb += 64;
    __syncthreads();
    bf16x8 af[4][2], bfr[2][2];
    #pragma unroll
    for(int mi=0;mi<4;mi++){
      int row = wr*64 + mi*16 + lr;
      af[mi][0] = ld8(&As[row*64 + ((g*8     ) ^ rs_a)]);
      af[mi][1] = ld8(&As[row*64 + ((g*8 + 32) ^ rs_a)]);
    }
    #pragma unroll
    for(int ni=0;ni<2;ni++){
      int row = wc*32 + ni*16 + lr;
      bfr[ni][0] = ld8(&Bs[row*64 + ((g*8     ) ^ rs_a)]);
      bfr[ni][1] = ld8(&Bs[row*64 + ((g*8 + 32) ^ rs_a)]);
    }
    #pragma unroll
    for(int mi=0;mi<4;mi++)
      #pragma unroll
      for(int ni=0;ni<2;ni++){
        acc[mi][ni] = MFMA(af[mi][0], bfr[ni][0], acc[mi][ni]);
        acc[mi][ni] = MFMA(af[mi][1], bfr[ni][1], acc[mi][ni]);
      }
    __syncthreads();
  }

  float bv[2];
  #pragma unroll
  for(int ni=0;ni<2;ni++) bv[ni] = bias[n0 + wc*32 + ni*16 + lr];
  #pragma unroll
  for(int mi=0;mi<4;mi++){
    int row = m0 + wr*64 + mi*16 + g*4;
    #pragma unroll
    for(int ni=0;ni<2;ni++){
      int col = n0 + wc*32 + ni*16 + lr;
      #pragma unroll
      for(int r=0;r<4;r++){
        float v = acc[mi][ni][r] + bv[ni];
        if constexpr(EPI==0)
          ((u16*)outp)[(size_t)(row + r)*N + col] = f2bf(v);
        else
          res[(size_t)(row + r)*N + col] += v;
      }
    }
  }
}

// ---------------- GEMM 256x256 8-phase (head) — r15 schedule (proven ~350us)
__global__ __launch_bounds__(512) void k_gemm256(const u16* __restrict__ A,
                                                 const u16* __restrict__ Bt,
                                                 float* __restrict__ out,
                                                 int M, int N, int K, int m_base){
  __shared__ __align__(16) u16 As[2][256*64];
  __shared__ __align__(16) u16 Bs[2][256*64];
  int t = threadIdx.x, l = t & 63, wid = t >> 6;
  int g = l >> 4, lr = l & 15;
  int m0 = m_base + blockIdx.x*256, n0 = blockIdx.y*256;
  f32x4 acc[2][16];
  #pragma unroll
  for(int mi=0;mi<2;mi++)
    #pragma unroll
    for(int i=0;i<16;i++) acc[mi][i] = f32x4{0.f,0.f,0.f,0.f};

  int srow = t >> 3;
  int scol = ((t & 7) ^ (srow & 7)) * 8;
  const int rs = (lr & 7) * 8;
  int nt = K >> 6;

  auto stage_half = [&](int jj, int h){
    int buf = jj & 1; int k0s = jj << 6;
    if(h < 2){
      #pragma unroll
      for(int c=0;c<2;c++){
        int rr = h*128 + c*64 + srow;
        gl_lds16(A + (size_t)(m0 + rr)*K + k0s + scol,
                 &As[buf][rr*64 + (t&7)*8]);
      }
    } else {
      #pragma unroll
      for(int c=0;c<2;c++){
        int rr = (h-2)*128 + c*64 + srow;
        gl_lds16(Bt + (size_t)(n0 + rr)*K + k0s + scol,
                 &Bs[buf][rr*64 + (t&7)*8]);
      }
    }
  };

  stage_half(0,0); stage_half(0,1); stage_half(0,2); stage_half(0,3);
  asm volatile("s_waitcnt vmcnt(2)" ::: "memory");
  __builtin_amdgcn_s_barrier();
  __builtin_amdgcn_sched_barrier(0);

  bf16x8 af[2][2];
  for(int j=0; j<nt; ++j){
    const u16* Ab = As[j & 1];
    const u16* Bb = Bs[j & 1];
    bool pf = (j + 1 < nt);
    #pragma unroll
    for(int q=0; q<4; ++q){
      if(q == 0){
        #pragma unroll
        for(int mi=0;mi<2;mi++){
          int row = wid*32 + mi*16 + lr;
          af[mi][0] = ld8(&Ab[row*64 + ((g*8     ) ^ rs)]);
          af[mi][1] = ld8(&Ab[row*64 + ((g*8 + 32) ^ rs)]);
        }
      }
      bf16x8 bfr[4][2];
      #pragma unroll
      for(int i=0;i<4;i++){
        int row = (q*4 + i)*16 + lr;
        bfr[i][0] = ld8(&Bb[row*64 + ((g*8     ) ^ rs)]);
        bfr[i][1] = ld8(&Bb[row*64 + ((g*8 + 32) ^ rs)]);
      }
      if(pf) stage_half(j+1, q);
      __builtin_amdgcn_s_barrier();
      __builtin_amdgcn_sched_barrier(0);
      __builtin_amdgcn_s_setprio(1);
      #pragma unroll
      for(int mi=0;mi<2;mi++)
        #pragma unroll
        for(int i=0;i<4;i++){
          acc[mi][q*4+i] = MFMA(af[mi][0], bfr[i][0], acc[mi][q*4+i]);
          acc[mi][q*4+i] = MFMA(af[mi][1], bfr[i][1], acc[mi][q*4+i]);
        }
      __builtin_amdgcn_s_setprio(0);
      if(q == 1) asm volatile("s_waitcnt vmcnt(4)" ::: "memory");
      if(q == 3) asm volatile("s_waitcnt vmcnt(2)" ::: "memory");
      __builtin_amdgcn_s_barrier();
      __builtin_amdgcn_sched_barrier(0);
    }
  }

  #pragma unroll
  for(int mi=0;mi<2;mi++){
    int row = m0 + wid*32 + mi*16 + g*4;
    #pragma unroll
    for(int i=0;i<16;i++){
      int col = n0 + i*16 + lr;
      #pragma unroll
      for(int r=0;r<4;r++)
        out[(size_t)(row + r)*N + col] = acc[mi][i][r];
    }
  }
}

// ---------------- head GEMM fallback (small-ws only): BK=32 reg-staged B
__global__ __launch_bounds__(256) void k_gemm_f32b(const u16* __restrict__ A,
                                                   const float* __restrict__ B,
                                                   float* __restrict__ out,
                                                   int M, int N, int K, int m_base){
  __shared__ __align__(16) u16 As[128*32];
  __shared__ __align__(16) u16 Bs[128*32];
  int t = threadIdx.x, l = t & 63, w = t >> 6;
  int g = l >> 4, lr = l & 15;
  int wr = w >> 1, wc = w & 1;
  int m0 = m_base + blockIdx.y*128, n0 = blockIdx.x*128;
  f32x4 acc[4][4];
  #pragma unroll
  for(int i=0;i<4;i++)
    #pragma unroll
    for(int j=0;j<4;j++) acc[i][j] = f32x4{0.f,0.f,0.f,0.f};

  int r0 = t >> 2, c0 = (t & 3)*8;
  const u16* pa0 = A + (size_t)(m0 + r0)*K + c0;
  const u16* pa1 = A + (size_t)(m0 + r0 + 64)*K + c0;
  u16* la0 = As + t*8;  u16* la1 = As + (t+256)*8;
  int br = t >> 1, bc = (t & 1)*16;
  const float* pb = B + (size_t)(n0 + br)*K + bc;

  for(int k0=0; k0<K; k0+=32){
    gl_lds16(pa0, la0); gl_lds16(pa1, la1);
    pa0 += 32; pa1 += 32;
    float4 f0 = ((const float4*)pb)[0];
    float4 f1 = ((const float4*)pb)[1];
    float4 f2 = ((const float4*)pb)[2];
    float4 f3 = ((const float4*)pb)[3];
    pb += 32;
    ushort4 u0{f2bf(f0.x),f2bf(f0.y),f2bf(f0.z),f2bf(f0.w)};
    ushort4 u1{f2bf(f1.x),f2bf(f1.y),f2bf(f1.z),f2bf(f1.w)};
    ushort4 u2{f2bf(f2.x),f2bf(f2.y),f2bf(f2.z),f2bf(f2.w)};
    ushort4 u3{f2bf(f3.x),f2bf(f3.y),f2bf(f3.z),f2bf(f3.w)};
    *(ushort4*)&Bs[br*32 + bc +  0] = u0;
    *(ushort4*)&Bs[br*32 + bc +  4] = u1;
    *(ushort4*)&Bs[br*32 + bc +  8] = u2;
    *(ushort4*)&Bs[br*32 + bc + 12] = u3;
    __syncthreads();
    bf16x8 af[4], bfr[4];
    #pragma unroll
    for(int mi=0;mi<4;mi++) af[mi]  = ld8(&As[(wr*64 + mi*16 + lr)*32 + g*8]);
    #pragma unroll
    for(int ni=0;ni<4;ni++) bfr[ni] = ld8(&Bs[(wc*64 + ni*16 + lr)*32 + g*8]);
    #pragma unroll
    for(int mi=0;mi<4;mi++)
      #pragma unroll
      for(int ni=0;ni<4;ni++)
        acc[mi][ni] = MFMA(af[mi], bfr[ni], acc[mi][ni]);
    __syncthreads();
  }

  #pragma unroll
  for(int mi=0;mi<4;mi++){
    int row = m0 + wr*64 + mi*16 + g*4;
    #pragma unroll
    for(int ni=0;ni<4;ni++){
      int col = n0 + wc*64 + ni*16 + lr;
      #pragma unroll
      for(int r=0;r<4;r++)
        out[(size_t)(row + r)*N + col] = acc[mi][ni][r];
    }
  }
}

// ---------------- flash attention, BALANCED causal pairing:
// grid (16,32); block handles q-tile bx AND q-tile (31-bx) sequentially
// -> uniform 33 KV-tiles per block (was 2..32, ~50% idle tail).
// QBLK=64, 4 waves x 16 q-rows (r13-verified geometry) + T14 reg prefetch,
// fixed-max softmax, interior fast path, XOR-swizzled V, MFMA row-sums.
__global__ __launch_bounds__(256) void k_attn(const u16* __restrict__ qkv,
                                              u16* __restrict__ atto){
  __shared__ __align__(16) u16 Ksm[64*72];
  __shared__ __align__(16) u16 Vsm[64*72];
  __shared__ __align__(16) u16 Psm[4][16*72];
  int t = threadIdx.x, l = t & 63, w = t >> 6, g = l >> 4, lr = l & 15;
  int bh = blockIdx.y; int b = bh >> 4, h = bh & 15, kvh = h >> 2;
  const float L2E = 1.44269504088896f;
  const float C1  = 0.125f * L2E;
  float slopeL = exp2f(-0.5f*(float)(h+1)) * L2E;
  float sLkt[4];
  #pragma unroll
  for(int kt=0;kt<4;kt++) sLkt[kt] = slopeL*(float)(kt*16+lr);

  bf16_t onev = (bf16_t)1.0f;
  bf16x8 onesb = {onev,onev,onev,onev,onev,onev,onev,onev};

  // T14 staging addresses (fixed per thread, independent of q-tile)
  int skey = t >> 3, sho = (t & 7)*8;                 // K: 1 int4 x2 halves
  int vkey0 = (t>>3)*2, vhd0 = (t&7)*8;               // V: 2 int4
  int4 kreg0, kreg1, vreg0, vreg1;
  auto issue = [&](int kb){
    const u16* kp = qkv + (size_t)(b*2048 + kb*64 + skey)*1536 + 1024 + kvh*64 + sho;
    kreg0 = *(const int4*)kp;
    kreg1 = *(const int4*)(kp + (size_t)32*1536);     // rows 32..63
    const u16* v0 = qkv + (size_t)(b*2048 + kb*64 + vkey0)*1536 + 1280 + kvh*64 + vhd0;
    vreg0 = *(const int4*)v0;
    vreg1 = *(const int4*)(v0 + 1536);
  };

  #pragma unroll
  for(int pass=0; pass<2; pass++){
    int qt = (pass == 0) ? blockIdx.x : (31 - blockIdx.x);
    int qb = qt*64;
    // Q fragments for this pass
    const u16* qp = qkv + (size_t)(b*2048 + qb + w*16 + lr)*1536 + h*64;
    bf16x8 qf0 = ld8(qp + g*8);
    bf16x8 qf1 = ld8(qp + 32 + g*8);

    f32x4 oacc[4];
    #pragma unroll
    for(int i=0;i<4;i++) oacc[i] = f32x4{0.f,0.f,0.f,0.f};
    f32x4 lsum = f32x4{0.f,0.f,0.f,0.f};

    int qmin_w = qb + w*16;
    int qmax_w = qmin_w + 15;
    int nkb = qt + 1;
    issue(0);
    for(int kb=0; kb<nkb; kb++){
      __syncthreads();                  // prior tile's LDS reads complete
      *(int4*)&Ksm[skey*72 + sho] = kreg0;
      *(int4*)&Ksm[(skey+32)*72 + sho] = kreg1;
      {
        const u16* ua = (const u16*)&vreg0; const u16* ub = (const u16*)&vreg1;
        #pragma unroll
        for(int j=0;j<8;j++){
          int row = vhd0 + j;
          int colp = vkey0 ^ ((row>>3)*8);
          unsigned pr = (unsigned)ua[j] | ((unsigned)ub[j]<<16);
          *(unsigned*)&Vsm[row*72 + colp] = pr;
        }
      }
      __syncthreads();                  // tile kb ready
      if(kb + 1 < nkb) issue(kb + 1);   // overlap next loads with compute
      if(kb*64 > qmax_w) continue;
      f32x4 sacc[4];
      #pragma unroll
      for(int kt=0;kt<4;kt++) sacc[kt] = f32x4{0.f,0.f,0.f,0.f};
      #pragma unroll
      for(int kt=0;kt<4;kt++){
        bf16x8 kf0 = ld8(&Ksm[(kt*16+lr)*72 + g*8]);
        bf16x8 kf1 = ld8(&Ksm[(kt*16+lr)*72 + 32 + g*8]);
        sacc[kt] = MFMA(qf0, kf0, sacc[kt]);
        sacc[kt] = MFMA(qf1, kf1, sacc[kt]);
      }
      if(kb*64 + 63 <= qmin_w){
        #pragma unroll
        for(int r=0;r<4;r++){
          int q = qb + w*16 + g*4 + r;
          float base = slopeL*(float)(kb*64 - q) - 8.0f*L2E;
          #pragma unroll
          for(int kt=0;kt<4;kt++){
            float f = fmaf(sacc[kt][r], C1, base + sLkt[kt]);
            Psm[w][(g*4+r)*72 + kt*16 + lr] = f2bf(exp2f(f));
          }
        }
      } else {
        #pragma unroll
        for(int r=0;r<4;r++){
          int q = qb + w*16 + g*4 + r;
          float base = slopeL*(float)(kb*64 - q) - 8.0f*L2E;
          #pragma unroll
          for(int kt=0;kt<4;kt++){
            int key = kb*64 + kt*16 + lr;
            float f = fmaf(sacc[kt][r], C1, base + sLkt[kt]);
            float p = (key <= q) ? exp2f(f) : 0.f;
            Psm[w][(g*4+r)*72 + kt*16 + lr] = f2bf(p);
          }
        }
      }
      #pragma unroll
      for(int ks=0;ks<2;ks++){
        bf16x8 pf = ld8(&Psm[w][lr*72 + ks*32 + g*8]);
        lsum = MFMA(pf, onesb, lsum);
        #pragma unroll
        for(int ht=0;ht<4;ht++){
          int row = ht*16 + lr;
          int colp = (ks*32 + g*8) ^ ((row>>3)*8);
          bf16x8 vf = ld8(&Vsm[row*72 + colp]);
          oacc[ht] = MFMA(pf, vf, oacc[ht]);
        }
      }
    }
    #pragma unroll
    for(int ht=0;ht<4;ht++){
      #pragma unroll
      for(int r=0;r<4;r++){
        float o = oacc[ht][r] / lsum[r];
        atto[(size_t)(b*2048 + qb + w*16 + g*4 + r)*1024 + h*64 + ht*16 + lr] = f2bf(o);
      }
    }
  }
}

extern "C" void kernel_launch(void* const* d_in, const int* in_sizes, int n_in,
                              void* d_out, int out_size, void* d_ws, size_t ws_size,
                              hipStream_t stream) {
  const float* tok_emb = (const float*)d_in[0];
  const float* ln1_s   = (const float*)d_in[1];
  const float* ln1_b   = (const float*)d_in[2];
  const float* qkv_w   = (const float*)d_in[3];
  const float* qkv_b   = (const float*)d_in[4];
  const float* proj_w  = (const float*)d_in[5];
  const float* proj_b  = (const float*)d_in[6];
  const float* ln2_s   = (const float*)d_in[7];
  const float* ln2_b   = (const float*)d_in[8];
  const float* fc1_w   = (const float*)d_in[9];
  const float* fc1_b   = (const float*)d_in[10];
  const float* fc2_w   = (const float*)d_in[11];
  const float* fc2_b   = (const float*)d_in[12];
  const float* lnf_s   = (const float*)d_in[13];
  const float* lnf_b   = (const float*)d_in[14];
  const int*   idx     = (const int*)d_in[15];

  // scratch plan inside d_out (524 MB, f32 logits written last):
  char* ob = (char*)d_out;
  float* xf32  = (float*)(ob);                                 //  0   .. 16.8 MB
  u16* qkv_bf  = (u16*)(ob + (size_t)16777216);                // 16.8 .. 29.4
  u16* atto_bf = (u16*)(ob + (size_t)29360128);                // 29.4 .. 37.7
  u16* mid_bf  = (u16*)(ob + (size_t)37748736);                // 37.7 .. 71.3
  u16* wt_qkv  = (u16*)(ob + (size_t)71303168);                // 71.3 .. 83.9
  u16* wt_proj = (u16*)(ob + (size_t)83886080);                // 83.9 .. 92.3
  u16* wt_fc1  = (u16*)(ob + (size_t)92274688);                // 92.3 ..125.8
  u16* wt_fc2  = (u16*)(ob + (size_t)125829120);               //125.8 ..159.4
  u16* h_bf    = (u16*)d_ws;                                   //  8.4 MB
  float* out   = (float*)d_out;

  bool big_ws = ws_size >= (size_t)(8388608 + 65536000);
  u16* te_bf = big_ws ? (u16*)((char*)d_ws + 8388608)
                      : (u16*)(ob + (size_t)294912000);

  k_prep<<<36096, 256, 0, stream>>>(tok_emb, te_bf, idx, xf32);
  k_convT<<<dim3(24,16,4), 256, 0, stream>>>(qkv_w,  wt_qkv, 1024, 1536);
  k_convT<<<dim3(16,16,4), 256, 0, stream>>>(proj_w, wt_proj, 1024, 1024);
  k_convT<<<dim3(64,16,4), 256, 0, stream>>>(fc1_w, wt_fc1, 1024, 4096);
  k_convT<<<dim3(16,64,4), 256, 0, stream>>>(fc2_w, wt_fc2, 4096, 1024);

  for(int l=0; l<4; l++){
    k_ln<<<4096, 256, 0, stream>>>(xf32, ln1_s + (size_t)l*1024, ln1_b + (size_t)l*1024, h_bf);
    k_gemm_n64<0><<<dim3(24,32), 256, 0, stream>>>(h_bf, wt_qkv + (size_t)l*1536*1024,
                                                   qkv_b + (size_t)l*1536,
                                                   qkv_bf, nullptr, 4096, 1536, 1024);
    k_attn<<<dim3(16,32), 256, 0, stream>>>(qkv_bf, atto_bf);
    k_gemm_n64<1><<<dim3(16,32), 256, 0, stream>>>(atto_bf, wt_proj + (size_t)l*1024*1024,
                                                   proj_b + (size_t)l*1024,
                                                   nullptr, xf32, 4096, 1024, 1024);
    k_ln<<<4096, 256, 0, stream>>>(xf32, ln2_s + (size_t)l*1024, ln2_b + (size_t)l*1024, h_bf);
    k_gemm<2,0><<<dim3(32,32), 256, 0, stream>>>(h_bf, wt_fc1 + (size_t)l*4096*1024,
                                                 fc1_b + (size_t)l*4096,
                                                 mid_bf, nullptr, 4096, 4096, 1024, 0);
    k_gemm_n64<1><<<dim3(16,32), 256, 0, stream>>>(mid_bf, wt_fc2 + (size_t)l*1024*4096,
                                                   fc2_b + (size_t)l*1024,
                                                   nullptr, xf32, 4096, 1024, 4096);
  }
  k_ln<<<4096, 256, 0, stream>>>(xf32, lnf_s, lnf_b, h_bf);

  if(big_ws){
    k_gemm256<<<dim3(16,125), 512, 0, stream>>>(h_bf, te_bf, out,
                                                4096, 32000, 1024, 0);
  } else {
    k_gemm256<<<dim3(9,125), 512, 0, stream>>>(h_bf, te_bf, out,
                                               4096, 32000, 1024, 0);
    k_gemm256<<<dim3(5,125), 512, 0, stream>>>(h_bf, te_bf, out,
                                               4096, 32000, 1024, 2816);
    k_gemm_f32b<<<dim3(250,4), 256, 0, stream>>>(h_bf, tok_emb, out,
                                                 4096, 32000, 1024, 2304);
  }
}

// Round 24
// 1454.338 us; speedup vs baseline: 1.0799x; 1.0017x over previous
//
#include <hip/hip_runtime.h>

#define DEV __device__ __forceinline__
typedef unsigned short u16;
typedef __bf16 bf16_t;
typedef bf16_t bf16x8 __attribute__((ext_vector_type(8)));
typedef float f32x4 __attribute__((ext_vector_type(4)));

DEV u16 f2bf(float f){ unsigned u=__float_as_uint(f); return (u16)((u + 0x7fffu + ((u>>16)&1u))>>16); }

DEV void gl_lds16(const void* g, void* l){
  __builtin_amdgcn_global_load_lds((__attribute__((address_space(1))) void*)g,
                                   (__attribute__((address_space(3))) void*)l, 16, 0, 0);
}
DEV f32x4 MFMA(bf16x8 a, bf16x8 b, f32x4 c){
  return __builtin_amdgcn_mfma_f32_16x16x32_bf16(a, b, c, 0, 0, 0);
}
DEV bf16x8 ld8(const u16* p){ return *(const bf16x8*)p; }

// ---------------- fused prep: tok_emb f32->bf16 convert + embedding gather
__global__ __launch_bounds__(256) void k_prep(const float* __restrict__ emb,
                                              u16* __restrict__ te,
                                              const int* __restrict__ idx,
                                              float* __restrict__ x){
  int b = blockIdx.x;
  if(b < 32000){
    int i = b*256 + threadIdx.x;          // < 8192000
    float4 v = ((const float4*)emb)[i];
    ushort4 o; o.x=f2bf(v.x); o.y=f2bf(v.y); o.z=f2bf(v.z); o.w=f2bf(v.w);
    ((ushort4*)te)[i] = o;
  } else {
    int row = b - 32000;                  // 0..4095
    int tok = idx[row];
    ((float4*)(x + (size_t)row*1024))[threadIdx.x] =
        ((const float4*)(emb + (size_t)tok*1024))[threadIdx.x];
  }
}

// ---------------- layernorm (fp32 in) -> bf16 out, row = 1024
__global__ __launch_bounds__(256) void k_ln(const float* __restrict__ x,
                                            const float* __restrict__ sc,
                                            const float* __restrict__ bi,
                                            u16* __restrict__ out){
  int row = blockIdx.x;
  const float* xr = x + (size_t)row*1024;
  float4 v = ((const float4*)xr)[threadIdx.x];
  float s = v.x+v.y+v.z+v.w;
  float q = v.x*v.x+v.y*v.y+v.z*v.z+v.w*v.w;
  #pragma unroll
  for(int m=1;m<64;m<<=1){ s += __shfl_xor(s,m); q += __shfl_xor(q,m); }
  __shared__ float ss[4], sq[4];
  int w = threadIdx.x>>6;
  if((threadIdx.x&63)==0){ ss[w]=s; sq[w]=q; }
  __syncthreads();
  s = ss[0]+ss[1]+ss[2]+ss[3];
  q = sq[0]+sq[1]+sq[2]+sq[3];
  float mu = s*(1.f/1024.f);
  float var = q*(1.f/1024.f) - mu*mu;
  float rs = rsqrtf(var + 1e-5f);
  float4 sv = ((const float4*)sc)[threadIdx.x];
  float4 bv = ((const float4*)bi)[threadIdx.x];
  ushort4 o;
  o.x = f2bf((v.x-mu)*rs*sv.x + bv.x);
  o.y = f2bf((v.y-mu)*rs*sv.y + bv.y);
  o.z = f2bf((v.z-mu)*rs*sv.z + bv.z);
  o.w = f2bf((v.w-mu)*rs*sv.w + bv.w);
  *(ushort4*)(out + (size_t)row*1024 + threadIdx.x*4) = o;
}

// ---------------- transpose + convert (64x64, vectorized): W[K][N] f32 -> Wt[N][K] bf16
__global__ __launch_bounds__(256) void k_convT(const float* __restrict__ W,
                                               u16* __restrict__ Wt, int K, int N){
  __shared__ float tile[64][68];
  size_t loff = (size_t)blockIdx.z * K * N;
  W  += loff;  Wt += loff;
  int n0 = blockIdx.x*64, k0 = blockIdx.y*64;
  int tx = threadIdx.x & 15, ty = threadIdx.x >> 4;   // 16 x 16
  #pragma unroll
  for(int r=0;r<4;r++){
    int row = ty + r*16;
    float4 v = *(const float4*)&W[(size_t)(k0+row)*N + n0 + tx*4];
    *(float4*)&tile[row][tx*4] = v;
  }
  __syncthreads();
  int nn = threadIdx.x >> 2, kq = threadIdx.x & 3;
  #pragma unroll
  for(int r=0;r<4;r++){
    int k = (kq + r*4)*4;
    ushort4 o;
    o.x = f2bf(tile[k+0][nn]); o.y = f2bf(tile[k+1][nn]);
    o.z = f2bf(tile[k+2][nn]); o.w = f2bf(tile[k+3][nn]);
    *(ushort4*)&Wt[(size_t)(n0+nn)*K + k0 + k] = o;
  }
}

// ---------------- GEMM 128x128 (2-barrier): C = A * Bt^T, BK=64, XOR swizzle
template<int EPI, int SWAP>
__global__ __launch_bounds__(256) void k_gemm(const u16* __restrict__ A,
                                              const u16* __restrict__ Bt,
                                              const float* __restrict__ bias,
                                              void* __restrict__ out,
                                              float* __restrict__ res,
                                              int M, int N, int K, int m_base){
  __shared__ __align__(16) u16 As[128*64];
  __shared__ __align__(16) u16 Bs[128*64];
  int t = threadIdx.x, l = t & 63, w = t >> 6;
  int g = l >> 4, lr = l & 15;
  int wr = w >> 1, wc = w & 1;
  int m0, n0;
  if constexpr(SWAP){ m0 = m_base + blockIdx.x*128; n0 = blockIdx.y*128; }
  else              { m0 = m_base + blockIdx.y*128; n0 = blockIdx.x*128; }
  f32x4 acc[4][4];
  #pragma unroll
  for(int i=0;i<4;i++)
    #pragma unroll
    for(int j=0;j<4;j++) acc[i][j] = f32x4{0.f,0.f,0.f,0.f};

  int sr = t >> 3;
  int sc = (((t & 7) ^ (sr & 7)) * 8);
  const u16* pa = A  + (size_t)(m0 + sr)*K + sc;
  const u16* pb = Bt + (size_t)(n0 + sr)*K + sc;
  u16* lda = As + t*8;
  u16* ldb = Bs + t*8;
  const int rs_a = (lr & 7)*8;

  for(int k0=0; k0<K; k0+=64){
    #pragma unroll
    for(int i=0;i<4;i++){
      gl_lds16(pa + (size_t)(i*32)*K, lda + i*2048);
      gl_lds16(pb + (size_t)(i*32)*K, ldb + i*2048);
    }
    pa += 64; pb += 64;
    __syncthreads();
    bf16x8 af[4][2], bfr[4][2];
    #pragma unroll
    for(int mi=0;mi<4;mi++){
      int row = wr*64 + mi*16 + lr;
      af[mi][0] = ld8(&As[row*64 + ((g*8     ) ^ rs_a)]);
      af[mi][1] = ld8(&As[row*64 + ((g*8 + 32) ^ rs_a)]);
    }
    #pragma unroll
    for(int ni=0;ni<4;ni++){
      int row = wc*64 + ni*16 + lr;
      bfr[ni][0] = ld8(&Bs[row*64 + ((g*8     ) ^ rs_a)]);
      bfr[ni][1] = ld8(&Bs[row*64 + ((g*8 + 32) ^ rs_a)]);
    }
    #pragma unroll
    for(int mi=0;mi<4;mi++)
      #pragma unroll
      for(int ni=0;ni<4;ni++){
        acc[mi][ni] = MFMA(af[mi][0], bfr[ni][0], acc[mi][ni]);
        acc[mi][ni] = MFMA(af[mi][1], bfr[ni][1], acc[mi][ni]);
      }
    __syncthreads();
  }

  float bv[4];
  #pragma unroll
  for(int ni=0;ni<4;ni++){
    if constexpr(EPI==3) bv[ni] = 0.f;
    else bv[ni] = bias[n0 + wc*64 + ni*16 + lr];
  }
  #pragma unroll
  for(int mi=0;mi<4;mi++){
    int row = m0 + wr*64 + mi*16 + g*4;
    #pragma unroll
    for(int ni=0;ni<4;ni++){
      int col = n0 + wc*64 + ni*16 + lr;
      #pragma unroll
      for(int r=0;r<4;r++){
        float v = acc[mi][ni][r] + bv[ni];
        size_t oidx = (size_t)(row + r)*N + col;
        if constexpr(EPI==0){
          ((u16*)out)[oidx] = f2bf(v);
        } else if constexpr(EPI==1){
          res[oidx] += v;
        } else if constexpr(EPI==2){
          float gv = 0.5f*v*(1.f + erff(v*0.70710678118654752f));
          ((u16*)out)[oidx] = f2bf(gv);
        } else {
          ((float*)out)[oidx] = v;   // f32 logits
        }
      }
    }
  }
}

// ---------------- GEMM 128x64 narrow: high-occupancy even-grid variant
// EPI: 0 = +bias -> bf16 out ; 1 = +bias, res(f32) += v
template<int EPI>
__global__ __launch_bounds__(256) void k_gemm_n64(const u16* __restrict__ A,
                                                  const u16* __restrict__ Bt,
                                                  const float* __restrict__ bias,
                                                  void* __restrict__ outp,
                                                  float* __restrict__ res,
                                                  int M, int N, int K){
  __shared__ __align__(16) u16 As[128*64];
  __shared__ __align__(16) u16 Bs[64*64];
  int t = threadIdx.x, l = t & 63, w = t >> 6;
  int g = l >> 4, lr = l & 15;
  int wr = w >> 1, wc = w & 1;
  int m0 = blockIdx.y*128, n0 = blockIdx.x*64;
  f32x4 acc[4][2];
  #pragma unroll
  for(int i=0;i<4;i++)
    #pragma unroll
    for(int j=0;j<2;j++) acc[i][j] = f32x4{0.f,0.f,0.f,0.f};

  int sr = t >> 3;
  int sc = (((t & 7) ^ (sr & 7)) * 8);
  const u16* pa = A  + (size_t)(m0 + sr)*K + sc;
  const u16* pb = Bt + (size_t)(n0 + sr)*K + sc;
  u16* lda = As + t*8;
  u16* ldb = Bs + t*8;
  const int rs_a = (lr & 7)*8;

  for(int k0=0; k0<K; k0+=64){
    #pragma unroll
    for(int i=0;i<4;i++)
      gl_lds16(pa + (size_t)(i*32)*K, lda + i*2048);
    #pragma unroll
    for(int i=0;i<2;i++)
      gl_lds16(pb + (size_t)(i*32)*K, ldb + i*2048);
    pa += 64; pb += 64;
    __syncthreads();
    bf16x8 af[4][2], bfr[2][2];
    #pragma unroll
    for(int mi=0;mi<4;mi++){
      int row = wr*64 + mi*16 + lr;
      af[mi][0] = ld8(&As[row*64 + ((g*8     ) ^ rs_a)]);
      af[mi][1] = ld8(&As[row*64 + ((g*8 + 32) ^ rs_a)]);
    }
    #pragma unroll
    for(int ni=0;ni<2;ni++){
      int row = wc*32 + ni*16 + lr;
      bfr[ni][0] = ld8(&Bs[row*64 + ((g*8     ) ^ rs_a)]);
      bfr[ni][1] = ld8(&Bs[row*64 + ((g*8 + 32) ^ rs_a)]);
    }
    #pragma unroll
    for(int mi=0;mi<4;mi++)
      #pragma unroll
      for(int ni=0;ni<2;ni++){
        acc[mi][ni] = MFMA(af[mi][0], bfr[ni][0], acc[mi][ni]);
        acc[mi][ni] = MFMA(af[mi][1], bfr[ni][1], acc[mi][ni]);
      }
    __syncthreads();
  }

  float bv[2];
  #pragma unroll
  for(int ni=0;ni<2;ni++) bv[ni] = bias[n0 + wc*32 + ni*16 + lr];
  #pragma unroll
  for(int mi=0;mi<4;mi++){
    int row = m0 + wr*64 + mi*16 + g*4;
    #pragma unroll
    for(int ni=0;ni<2;ni++){
      int col = n0 + wc*32 + ni*16 + lr;
      #pragma unroll
      for(int r=0;r<4;r++){
        float v = acc[mi][ni][r] + bv[ni];
        if constexpr(EPI==0)
          ((u16*)outp)[(size_t)(row + r)*N + col] = f2bf(v);
        else
          res[(size_t)(row + r)*N + col] += v;
      }
    }
  }
}

// ---------------- GEMM 256x256 8-phase (head) — r15 schedule + T1 XCD swizzle:
// bijective chunked remap keeps the 16 row-blocks sharing each B panel on one
// XCD so the panel stays in that XCD's L2 (write stream was thrashing L3).
__global__ __launch_bounds__(512) void k_gemm256(const u16* __restrict__ A,
                                                 const u16* __restrict__ Bt,
                                                 float* __restrict__ out,
                                                 int M, int N, int K, int m_base){
  __shared__ __align__(16) u16 As[2][256*64];
  __shared__ __align__(16) u16 Bs[2][256*64];
  int t = threadIdx.x, l = t & 63, wid = t >> 6;
  int g = l >> 4, lr = l & 15;
  // T1: dispatch-linear id -> chunked work id (m204 bijective form)
  int nwg = gridDim.x * gridDim.y;
  int lin = blockIdx.x + gridDim.x * blockIdx.y;
  int qch = nwg >> 3, rch = nwg & 7;
  int xcd = lin & 7, slot = lin >> 3;
  int work = (xcd < rch ? xcd*(qch+1) : rch*(qch+1) + (xcd-rch)*qch) + slot;
  int wx = work % gridDim.x;           // row-tile
  int wy = work / gridDim.x;           // col-tile (B panel)
  int m0 = m_base + wx*256, n0 = wy*256;
  f32x4 acc[2][16];
  #pragma unroll
  for(int mi=0;mi<2;mi++)
    #pragma unroll
    for(int i=0;i<16;i++) acc[mi][i] = f32x4{0.f,0.f,0.f,0.f};

  int srow = t >> 3;
  int scol = ((t & 7) ^ (srow & 7)) * 8;
  const int rs = (lr & 7) * 8;
  int nt = K >> 6;

  auto stage_half = [&](int jj, int h){
    int buf = jj & 1; int k0s = jj << 6;
    if(h < 2){
      #pragma unroll
      for(int c=0;c<2;c++){
        int rr = h*128 + c*64 + srow;
        gl_lds16(A + (size_t)(m0 + rr)*K + k0s + scol,
                 &As[buf][rr*64 + (t&7)*8]);
      }
    } else {
      #pragma unroll
      for(int c=0;c<2;c++){
        int rr = (h-2)*128 + c*64 + srow;
        gl_lds16(Bt + (size_t)(n0 + rr)*K + k0s + scol,
                 &Bs[buf][rr*64 + (t&7)*8]);
      }
    }
  };

  stage_half(0,0); stage_half(0,1); stage_half(0,2); stage_half(0,3);
  asm volatile("s_waitcnt vmcnt(2)" ::: "memory");
  __builtin_amdgcn_s_barrier();
  __builtin_amdgcn_sched_barrier(0);

  bf16x8 af[2][2];
  for(int j=0; j<nt; ++j){
    const u16* Ab = As[j & 1];
    const u16* Bb = Bs[j & 1];
    bool pf = (j + 1 < nt);
    #pragma unroll
    for(int q=0; q<4; ++q){
      if(q == 0){
        #pragma unroll
        for(int mi=0;mi<2;mi++){
          int row = wid*32 + mi*16 + lr;
          af[mi][0] = ld8(&Ab[row*64 + ((g*8     ) ^ rs)]);
          af[mi][1] = ld8(&Ab[row*64 + ((g*8 + 32) ^ rs)]);
        }
      }
      bf16x8 bfr[4][2];
      #pragma unroll
      for(int i=0;i<4;i++){
        int row = (q*4 + i)*16 + lr;
        bfr[i][0] = ld8(&Bb[row*64 + ((g*8     ) ^ rs)]);
        bfr[i][1] = ld8(&Bb[row*64 + ((g*8 + 32) ^ rs)]);
      }
      if(pf) stage_half(j+1, q);
      __builtin_amdgcn_s_barrier();
      __builtin_amdgcn_sched_barrier(0);
      __builtin_amdgcn_s_setprio(1);
      #pragma unroll
      for(int mi=0;mi<2;mi++)
        #pragma unroll
        for(int i=0;i<4;i++){
          acc[mi][q*4+i] = MFMA(af[mi][0], bfr[i][0], acc[mi][q*4+i]);
          acc[mi][q*4+i] = MFMA(af[mi][1], bfr[i][1], acc[mi][q*4+i]);
        }
      __builtin_amdgcn_s_setprio(0);
      if(q == 1) asm volatile("s_waitcnt vmcnt(4)" ::: "memory");
      if(q == 3) asm volatile("s_waitcnt vmcnt(2)" ::: "memory");
      __builtin_amdgcn_s_barrier();
      __builtin_amdgcn_sched_barrier(0);
    }
  }

  #pragma unroll
  for(int mi=0;mi<2;mi++){
    int row = m0 + wid*32 + mi*16 + g*4;
    #pragma unroll
    for(int i=0;i<16;i++){
      int col = n0 + i*16 + lr;
      #pragma unroll
      for(int r=0;r<4;r++)
        out[(size_t)(row + r)*N + col] = acc[mi][i][r];
    }
  }
}

// ---------------- head GEMM fallback (small-ws only): BK=32 reg-staged B
__global__ __launch_bounds__(256) void k_gemm_f32b(const u16* __restrict__ A,
                                                   const float* __restrict__ B,
                                                   float* __restrict__ out,
                                                   int M, int N, int K, int m_base){
  __shared__ __align__(16) u16 As[128*32];
  __shared__ __align__(16) u16 Bs[128*32];
  int t = threadIdx.x, l = t & 63, w = t >> 6;
  int g = l >> 4, lr = l & 15;
  int wr = w >> 1, wc = w & 1;
  int m0 = m_base + blockIdx.y*128, n0 = blockIdx.x*128;
  f32x4 acc[4][4];
  #pragma unroll
  for(int i=0;i<4;i++)
    #pragma unroll
    for(int j=0;j<4;j++) acc[i][j] = f32x4{0.f,0.f,0.f,0.f};

  int r0 = t >> 2, c0 = (t & 3)*8;
  const u16* pa0 = A + (size_t)(m0 + r0)*K + c0;
  const u16* pa1 = A + (size_t)(m0 + r0 + 64)*K + c0;
  u16* la0 = As + t*8;  u16* la1 = As + (t+256)*8;
  int br = t >> 1, bc = (t & 1)*16;
  const float* pb = B + (size_t)(n0 + br)*K + bc;

  for(int k0=0; k0<K; k0+=32){
    gl_lds16(pa0, la0); gl_lds16(pa1, la1);
    pa0 += 32; pa1 += 32;
    float4 f0 = ((const float4*)pb)[0];
    float4 f1 = ((const float4*)pb)[1];
    float4 f2 = ((const float4*)pb)[2];
    float4 f3 = ((const float4*)pb)[3];
    pb += 32;
    ushort4 u0{f2bf(f0.x),f2bf(f0.y),f2bf(f0.z),f2bf(f0.w)};
    ushort4 u1{f2bf(f1.x),f2bf(f1.y),f2bf(f1.z),f2bf(f1.w)};
    ushort4 u2{f2bf(f2.x),f2bf(f2.y),f2bf(f2.z),f2bf(f2.w)};
    ushort4 u3{f2bf(f3.x),f2bf(f3.y),f2bf(f3.z),f2bf(f3.w)};
    *(ushort4*)&Bs[br*32 + bc +  0] = u0;
    *(ushort4*)&Bs[br*32 + bc +  4] = u1;
    *(ushort4*)&Bs[br*32 + bc +  8] = u2;
    *(ushort4*)&Bs[br*32 + bc + 12] = u3;
    __syncthreads();
    bf16x8 af[4], bfr[4];
    #pragma unroll
    for(int mi=0;mi<4;mi++) af[mi]  = ld8(&As[(wr*64 + mi*16 + lr)*32 + g*8]);
    #pragma unroll
    for(int ni=0;ni<4;ni++) bfr[ni] = ld8(&Bs[(wc*64 + ni*16 + lr)*32 + g*8]);
    #pragma unroll
    for(int mi=0;mi<4;mi++)
      #pragma unroll
      for(int ni=0;ni<4;ni++)
        acc[mi][ni] = MFMA(af[mi], bfr[ni], acc[mi][ni]);
    __syncthreads();
  }

  #pragma unroll
  for(int mi=0;mi<4;mi++){
    int row = m0 + wr*64 + mi*16 + g*4;
    #pragma unroll
    for(int ni=0;ni<4;ni++){
      int col = n0 + wc*64 + ni*16 + lr;
      #pragma unroll
      for(int r=0;r<4;r++)
        out[(size_t)(row + r)*N + col] = acc[mi][ni][r];
    }
  }
}

// ---------------- flash attention, BALANCED causal pairing (r23-verified):
// grid (16,32); block handles q-tile bx AND q-tile (31-bx) sequentially.
__global__ __launch_bounds__(256) void k_attn(const u16* __restrict__ qkv,
                                              u16* __restrict__ atto){
  __shared__ __align__(16) u16 Ksm[64*72];
  __shared__ __align__(16) u16 Vsm[64*72];
  __shared__ __align__(16) u16 Psm[4][16*72];
  int t = threadIdx.x, l = t & 63, w = t >> 6, g = l >> 4, lr = l & 15;
  int bh = blockIdx.y; int b = bh >> 4, h = bh & 15, kvh = h >> 2;
  const float L2E = 1.44269504088896f;
  const float C1  = 0.125f * L2E;
  float slopeL = exp2f(-0.5f*(float)(h+1)) * L2E;
  float sLkt[4];
  #pragma unroll
  for(int kt=0;kt<4;kt++) sLkt[kt] = slopeL*(float)(kt*16+lr);

  bf16_t onev = (bf16_t)1.0f;
  bf16x8 onesb = {onev,onev,onev,onev,onev,onev,onev,onev};

  int skey = t >> 3, sho = (t & 7)*8;
  int vkey0 = (t>>3)*2, vhd0 = (t&7)*8;
  int4 kreg0, kreg1, vreg0, vreg1;
  auto issue = [&](int kb){
    const u16* kp = qkv + (size_t)(b*2048 + kb*64 + skey)*1536 + 1024 + kvh*64 + sho;
    kreg0 = *(const int4*)kp;
    kreg1 = *(const int4*)(kp + (size_t)32*1536);
    const u16* v0 = qkv + (size_t)(b*2048 + kb*64 + vkey0)*1536 + 1280 + kvh*64 + vhd0;
    vreg0 = *(const int4*)v0;
    vreg1 = *(const int4*)(v0 + 1536);
  };

  #pragma unroll
  for(int pass=0; pass<2; pass++){
    int qt = (pass == 0) ? blockIdx.x : (31 - blockIdx.x);
    int qb = qt*64;
    const u16* qp = qkv + (size_t)(b*2048 + qb + w*16 + lr)*1536 + h*64;
    bf16x8 qf0 = ld8(qp + g*8);
    bf16x8 qf1 = ld8(qp + 32 + g*8);

    f32x4 oacc[4];
    #pragma unroll
    for(int i=0;i<4;i++) oacc[i] = f32x4{0.f,0.f,0.f,0.f};
    f32x4 lsum = f32x4{0.f,0.f,0.f,0.f};

    int qmin_w = qb + w*16;
    int qmax_w = qmin_w + 15;
    int nkb = qt + 1;
    issue(0);
    for(int kb=0; kb<nkb; kb++){
      __syncthreads();
      *(int4*)&Ksm[skey*72 + sho] = kreg0;
      *(int4*)&Ksm[(skey+32)*72 + sho] = kreg1;
      {
        const u16* ua = (const u16*)&vreg0; const u16* ub = (const u16*)&vreg1;
        #pragma unroll
        for(int j=0;j<8;j++){
          int row = vhd0 + j;
          int colp = vkey0 ^ ((row>>3)*8);
          unsigned pr = (unsigned)ua[j] | ((unsigned)ub[j]<<16);
          *(unsigned*)&Vsm[row*72 + colp] = pr;
        }
      }
      __syncthreads();
      if(kb + 1 < nkb) issue(kb + 1);
      if(kb*64 > qmax_w) continue;
      f32x4 sacc[4];
      #pragma unroll
      for(int kt=0;kt<4;kt++) sacc[kt] = f32x4{0.f,0.f,0.f,0.f};
      #pragma unroll
      for(int kt=0;kt<4;kt++){
        bf16x8 kf0 = ld8(&Ksm[(kt*16+lr)*72 + g*8]);
        bf16x8 kf1 = ld8(&Ksm[(kt*16+lr)*72 + 32 + g*8]);
        sacc[kt] = MFMA(qf0, kf0, sacc[kt]);
        sacc[kt] = MFMA(qf1, kf1, sacc[kt]);
      }
      if(kb*64 + 63 <= qmin_w){
        #pragma unroll
        for(int r=0;r<4;r++){
          int q = qb + w*16 + g*4 + r;
          float base = slopeL*(float)(kb*64 - q) - 8.0f*L2E;
          #pragma unroll
          for(int kt=0;kt<4;kt++){
            float f = fmaf(sacc[kt][r], C1, base + sLkt[kt]);
            Psm[w][(g*4+r)*72 + kt*16 + lr] = f2bf(exp2f(f));
          }
        }
      } else {
        #pragma unroll
        for(int r=0;r<4;r++){
          int q = qb + w*16 + g*4 + r;
          float base = slopeL*(float)(kb*64 - q) - 8.0f*L2E;
          #pragma unroll
          for(int kt=0;kt<4;kt++){
            int key = kb*64 + kt*16 + lr;
            float f = fmaf(sacc[kt][r], C1, base + sLkt[kt]);
            float p = (key <= q) ? exp2f(f) : 0.f;
            Psm[w][(g*4+r)*72 + kt*16 + lr] = f2bf(p);
          }
        }
      }
      #pragma unroll
      for(int ks=0;ks<2;ks++){
        bf16x8 pf = ld8(&Psm[w][lr*72 + ks*32 + g*8]);
        lsum = MFMA(pf, onesb, lsum);
        #pragma unroll
        for(int ht=0;ht<4;ht++){
          int row = ht*16 + lr;
          int colp = (ks*32 + g*8) ^ ((row>>3)*8);
          bf16x8 vf = ld8(&Vsm[row*72 + colp]);
          oacc[ht] = MFMA(pf, vf, oacc[ht]);
        }
      }
    }
    #pragma unroll
    for(int ht=0;ht<4;ht++){
      #pragma unroll
      for(int r=0;r<4;r++){
        float o = oacc[ht][r] / lsum[r];
        atto[(size_t)(b*2048 + qb + w*16 + g*4 + r)*1024 + h*64 + ht*16 + lr] = f2bf(o);
      }
    }
  }
}

extern "C" void kernel_launch(void* const* d_in, const int* in_sizes, int n_in,
                              void* d_out, int out_size, void* d_ws, size_t ws_size,
                              hipStream_t stream) {
  const float* tok_emb = (const float*)d_in[0];
  const float* ln1_s   = (const float*)d_in[1];
  const float* ln1_b   = (const float*)d_in[2];
  const float* qkv_w   = (const float*)d_in[3];
  const float* qkv_b   = (const float*)d_in[4];
  const float* proj_w  = (const float*)d_in[5];
  const float* proj_b  = (const float*)d_in[6];
  const float* ln2_s   = (const float*)d_in[7];
  const float* ln2_b   = (const float*)d_in[8];
  const float* fc1_w   = (const float*)d_in[9];
  const float* fc1_b   = (const float*)d_in[10];
  const float* fc2_w   = (const float*)d_in[11];
  const float* fc2_b   = (const float*)d_in[12];
  const float* lnf_s   = (const float*)d_in[13];
  const float* lnf_b   = (const float*)d_in[14];
  const int*   idx     = (const int*)d_in[15];

  // scratch plan inside d_out (524 MB, f32 logits written last):
  char* ob = (char*)d_out;
  float* xf32  = (float*)(ob);                                 //  0   .. 16.8 MB
  u16* qkv_bf  = (u16*)(ob + (size_t)16777216);                // 16.8 .. 29.4
  u16* atto_bf = (u16*)(ob + (size_t)29360128);                // 29.4 .. 37.7
  u16* mid_bf  = (u16*)(ob + (size_t)37748736);                // 37.7 .. 71.3
  u16* wt_qkv  = (u16*)(ob + (size_t)71303168);                // 71.3 .. 83.9
  u16* wt_proj = (u16*)(ob + (size_t)83886080);                // 83.9 .. 92.3
  u16* wt_fc1  = (u16*)(ob + (size_t)92274688);                // 92.3 ..125.8
  u16* wt_fc2  = (u16*)(ob + (size_t)125829120);               //125.8 ..159.4
  u16* h_bf    = (u16*)d_ws;                                   //  8.4 MB
  float* out   = (float*)d_out;

  bool big_ws = ws_size >= (size_t)(8388608 + 65536000);
  u16* te_bf = big_ws ? (u16*)((char*)d_ws + 8388608)
                      : (u16*)(ob + (size_t)294912000);

  k_prep<<<36096, 256, 0, stream>>>(tok_emb, te_bf, idx, xf32);
  k_convT<<<dim3(24,16,4), 256, 0, stream>>>(qkv_w,  wt_qkv, 1024, 1536);
  k_convT<<<dim3(16,16,4), 256, 0, stream>>>(proj_w, wt_proj, 1024, 1024);
  k_convT<<<dim3(64,16,4), 256, 0, stream>>>(fc1_w, wt_fc1, 1024, 4096);
  k_convT<<<dim3(16,64,4), 256, 0, stream>>>(fc2_w, wt_fc2, 4096, 1024);

  for(int l=0; l<4; l++){
    k_ln<<<4096, 256, 0, stream>>>(xf32, ln1_s + (size_t)l*1024, ln1_b + (size_t)l*1024, h_bf);
    k_gemm_n64<0><<<dim3(24,32), 256, 0, stream>>>(h_bf, wt_qkv + (size_t)l*1536*1024,
                                                   qkv_b + (size_t)l*1536,
                                                   qkv_bf, nullptr, 4096, 1536, 1024);
    k_attn<<<dim3(16,32), 256, 0, stream>>>(qkv_bf, atto_bf);
    k_gemm_n64<1><<<dim3(16,32), 256, 0, stream>>>(atto_bf, wt_proj + (size_t)l*1024*1024,
                                                   proj_b + (size_t)l*1024,
                                                   nullptr, xf32, 4096, 1024, 1024);
    k_ln<<<4096, 256, 0, stream>>>(xf32, ln2_s + (size_t)l*1024, ln2_b + (size_t)l*1024, h_bf);
    k_gemm<2,0><<<dim3(32,32), 256, 0, stream>>>(h_bf, wt_fc1 + (size_t)l*4096*1024,
                                                 fc1_b + (size_t)l*4096,
                                                 mid_bf, nullptr, 4096, 4096, 1024, 0);
    k_gemm_n64<1><<<dim3(16,32), 256, 0, stream>>>(mid_bf, wt_fc2 + (size_t)l*1024*4096,
                                                   fc2_b + (size_t)l*1024,
                                                   nullptr, xf32, 4096, 1024, 4096);
  }
  k_ln<<<4096, 256, 0, stream>>>(xf32, lnf_s, lnf_b, h_bf);

  if(big_ws){
    k_gemm256<<<dim3(16,125), 512, 0, stream>>>(h_bf, te_bf, out,
                                                4096, 32000, 1024, 0);
  } else {
    k_gemm256<<<dim3(9,125), 512, 0, stream>>>(h_bf, te_bf, out,
                                               4096, 32000, 1024, 0);
    k_gemm256<<<dim3(5,125), 512, 0, stream>>>(h_bf, te_bf, out,
                                               4096, 32000, 1024, 2816);
    k_gemm_f32b<<<dim3(250,4), 256, 0, stream>>>(h_bf, tok_emb, out,
                                                 4096, 32000, 1024, 2304);
  }
}

// Round 25
// 1451.974 us; speedup vs baseline: 1.0817x; 1.0016x over previous
//
#include <hip/hip_runtime.h>

#define DEV __device__ __forceinline__
typedef unsigned short u16;
typedef __bf16 bf16_t;
typedef bf16_t bf16x8 __attribute__((ext_vector_type(8)));
typedef float f32x4 __attribute__((ext_vector_type(4)));

DEV u16 f2bf(float f){ unsigned u=__float_as_uint(f); return (u16)((u + 0x7fffu + ((u>>16)&1u))>>16); }

DEV void gl_lds16(const void* g, void* l){
  __builtin_amdgcn_global_load_lds((__attribute__((address_space(1))) void*)g,
                                   (__attribute__((address_space(3))) void*)l, 16, 0, 0);
}
DEV f32x4 MFMA(bf16x8 a, bf16x8 b, f32x4 c){
  return __builtin_amdgcn_mfma_f32_16x16x32_bf16(a, b, c, 0, 0, 0);
}
DEV bf16x8 ld8(const u16* p){ return *(const bf16x8*)p; }

// ---------------- fused prep: tok_emb f32->bf16 convert + embedding gather
__global__ __launch_bounds__(256) void k_prep(const float* __restrict__ emb,
                                              u16* __restrict__ te,
                                              const int* __restrict__ idx,
                                              float* __restrict__ x){
  int b = blockIdx.x;
  if(b < 32000){
    int i = b*256 + threadIdx.x;          // < 8192000
    float4 v = ((const float4*)emb)[i];
    ushort4 o; o.x=f2bf(v.x); o.y=f2bf(v.y); o.z=f2bf(v.z); o.w=f2bf(v.w);
    ((ushort4*)te)[i] = o;
  } else {
    int row = b - 32000;                  // 0..4095
    int tok = idx[row];
    ((float4*)(x + (size_t)row*1024))[threadIdx.x] =
        ((const float4*)(emb + (size_t)tok*1024))[threadIdx.x];
  }
}

// ---------------- layernorm (fp32 in) -> bf16 out, row = 1024
__global__ __launch_bounds__(256) void k_ln(const float* __restrict__ x,
                                            const float* __restrict__ sc,
                                            const float* __restrict__ bi,
                                            u16* __restrict__ out){
  int row = blockIdx.x;
  const float* xr = x + (size_t)row*1024;
  float4 v = ((const float4*)xr)[threadIdx.x];
  float s = v.x+v.y+v.z+v.w;
  float q = v.x*v.x+v.y*v.y+v.z*v.z+v.w*v.w;
  #pragma unroll
  for(int m=1;m<64;m<<=1){ s += __shfl_xor(s,m); q += __shfl_xor(q,m); }
  __shared__ float ss[4], sq[4];
  int w = threadIdx.x>>6;
  if((threadIdx.x&63)==0){ ss[w]=s; sq[w]=q; }
  __syncthreads();
  s = ss[0]+ss[1]+ss[2]+ss[3];
  q = sq[0]+sq[1]+sq[2]+sq[3];
  float mu = s*(1.f/1024.f);
  float var = q*(1.f/1024.f) - mu*mu;
  float rs = rsqrtf(var + 1e-5f);
  float4 sv = ((const float4*)sc)[threadIdx.x];
  float4 bv = ((const float4*)bi)[threadIdx.x];
  ushort4 o;
  o.x = f2bf((v.x-mu)*rs*sv.x + bv.x);
  o.y = f2bf((v.y-mu)*rs*sv.y + bv.y);
  o.z = f2bf((v.z-mu)*rs*sv.z + bv.z);
  o.w = f2bf((v.w-mu)*rs*sv.w + bv.w);
  *(ushort4*)(out + (size_t)row*1024 + threadIdx.x*4) = o;
}

// ---------------- transpose + convert (64x64, vectorized): W[K][N] f32 -> Wt[N][K] bf16
__global__ __launch_bounds__(256) void k_convT(const float* __restrict__ W,
                                               u16* __restrict__ Wt, int K, int N){
  __shared__ float tile[64][68];
  size_t loff = (size_t)blockIdx.z * K * N;
  W  += loff;  Wt += loff;
  int n0 = blockIdx.x*64, k0 = blockIdx.y*64;
  int tx = threadIdx.x & 15, ty = threadIdx.x >> 4;   // 16 x 16
  #pragma unroll
  for(int r=0;r<4;r++){
    int row = ty + r*16;
    float4 v = *(const float4*)&W[(size_t)(k0+row)*N + n0 + tx*4];
    *(float4*)&tile[row][tx*4] = v;
  }
  __syncthreads();
  int nn = threadIdx.x >> 2, kq = threadIdx.x & 3;
  #pragma unroll
  for(int r=0;r<4;r++){
    int k = (kq + r*4)*4;
    ushort4 o;
    o.x = f2bf(tile[k+0][nn]); o.y = f2bf(tile[k+1][nn]);
    o.z = f2bf(tile[k+2][nn]); o.w = f2bf(tile[k+3][nn]);
    *(ushort4*)&Wt[(size_t)(n0+nn)*K + k0 + k] = o;
  }
}

// ---------------- GEMM 128x128 (2-barrier): C = A * Bt^T, BK=64, XOR swizzle
template<int EPI, int SWAP>
__global__ __launch_bounds__(256) void k_gemm(const u16* __restrict__ A,
                                              const u16* __restrict__ Bt,
                                              const float* __restrict__ bias,
                                              void* __restrict__ out,
                                              float* __restrict__ res,
                                              int M, int N, int K, int m_base){
  __shared__ __align__(16) u16 As[128*64];
  __shared__ __align__(16) u16 Bs[128*64];
  int t = threadIdx.x, l = t & 63, w = t >> 6;
  int g = l >> 4, lr = l & 15;
  int wr = w >> 1, wc = w & 1;
  int m0, n0;
  if constexpr(SWAP){ m0 = m_base + blockIdx.x*128; n0 = blockIdx.y*128; }
  else              { m0 = m_base + blockIdx.y*128; n0 = blockIdx.x*128; }
  f32x4 acc[4][4];
  #pragma unroll
  for(int i=0;i<4;i++)
    #pragma unroll
    for(int j=0;j<4;j++) acc[i][j] = f32x4{0.f,0.f,0.f,0.f};

  int sr = t >> 3;
  int sc = (((t & 7) ^ (sr & 7)) * 8);
  const u16* pa = A  + (size_t)(m0 + sr)*K + sc;
  const u16* pb = Bt + (size_t)(n0 + sr)*K + sc;
  u16* lda = As + t*8;
  u16* ldb = Bs + t*8;
  const int rs_a = (lr & 7)*8;

  for(int k0=0; k0<K; k0+=64){
    #pragma unroll
    for(int i=0;i<4;i++){
      gl_lds16(pa + (size_t)(i*32)*K, lda + i*2048);
      gl_lds16(pb + (size_t)(i*32)*K, ldb + i*2048);
    }
    pa += 64; pb += 64;
    __syncthreads();
    bf16x8 af[4][2], bfr[4][2];
    #pragma unroll
    for(int mi=0;mi<4;mi++){
      int row = wr*64 + mi*16 + lr;
      af[mi][0] = ld8(&As[row*64 + ((g*8     ) ^ rs_a)]);
      af[mi][1] = ld8(&As[row*64 + ((g*8 + 32) ^ rs_a)]);
    }
    #pragma unroll
    for(int ni=0;ni<4;ni++){
      int row = wc*64 + ni*16 + lr;
      bfr[ni][0] = ld8(&Bs[row*64 + ((g*8     ) ^ rs_a)]);
      bfr[ni][1] = ld8(&Bs[row*64 + ((g*8 + 32) ^ rs_a)]);
    }
    #pragma unroll
    for(int mi=0;mi<4;mi++)
      #pragma unroll
      for(int ni=0;ni<4;ni++){
        acc[mi][ni] = MFMA(af[mi][0], bfr[ni][0], acc[mi][ni]);
        acc[mi][ni] = MFMA(af[mi][1], bfr[ni][1], acc[mi][ni]);
      }
    __syncthreads();
  }

  float bv[4];
  #pragma unroll
  for(int ni=0;ni<4;ni++){
    if constexpr(EPI==3) bv[ni] = 0.f;
    else bv[ni] = bias[n0 + wc*64 + ni*16 + lr];
  }
  #pragma unroll
  for(int mi=0;mi<4;mi++){
    int row = m0 + wr*64 + mi*16 + g*4;
    #pragma unroll
    for(int ni=0;ni<4;ni++){
      int col = n0 + wc*64 + ni*16 + lr;
      #pragma unroll
      for(int r=0;r<4;r++){
        float v = acc[mi][ni][r] + bv[ni];
        size_t oidx = (size_t)(row + r)*N + col;
        if constexpr(EPI==0){
          ((u16*)out)[oidx] = f2bf(v);
        } else if constexpr(EPI==1){
          res[oidx] += v;
        } else if constexpr(EPI==2){
          float gv = 0.5f*v*(1.f + erff(v*0.70710678118654752f));
          ((u16*)out)[oidx] = f2bf(gv);
        } else {
          ((float*)out)[oidx] = v;   // f32 logits
        }
      }
    }
  }
}

// ---------------- GEMM 128x64 narrow: high-occupancy even-grid variant
// EPI: 0 = +bias -> bf16 out ; 1 = +bias, res(f32) += v
template<int EPI>
__global__ __launch_bounds__(256) void k_gemm_n64(const u16* __restrict__ A,
                                                  const u16* __restrict__ Bt,
                                                  const float* __restrict__ bias,
                                                  void* __restrict__ outp,
                                                  float* __restrict__ res,
                                                  int M, int N, int K){
  __shared__ __align__(16) u16 As[128*64];
  __shared__ __align__(16) u16 Bs[64*64];
  int t = threadIdx.x, l = t & 63, w = t >> 6;
  int g = l >> 4, lr = l & 15;
  int wr = w >> 1, wc = w & 1;
  int m0 = blockIdx.y*128, n0 = blockIdx.x*64;
  f32x4 acc[4][2];
  #pragma unroll
  for(int i=0;i<4;i++)
    #pragma unroll
    for(int j=0;j<2;j++) acc[i][j] = f32x4{0.f,0.f,0.f,0.f};

  int sr = t >> 3;
  int sc = (((t & 7) ^ (sr & 7)) * 8);
  const u16* pa = A  + (size_t)(m0 + sr)*K + sc;
  const u16* pb = Bt + (size_t)(n0 + sr)*K + sc;
  u16* lda = As + t*8;
  u16* ldb = Bs + t*8;
  const int rs_a = (lr & 7)*8;

  for(int k0=0; k0<K; k0+=64){
    #pragma unroll
    for(int i=0;i<4;i++)
      gl_lds16(pa + (size_t)(i*32)*K, lda + i*2048);
    #pragma unroll
    for(int i=0;i<2;i++)
      gl_lds16(pb + (size_t)(i*32)*K, ldb + i*2048);
    pa += 64; pb += 64;
    __syncthreads();
    bf16x8 af[4][2], bfr[2][2];
    #pragma unroll
    for(int mi=0;mi<4;mi++){
      int row = wr*64 + mi*16 + lr;
      af[mi][0] = ld8(&As[row*64 + ((g*8     ) ^ rs_a)]);
      af[mi][1] = ld8(&As[row*64 + ((g*8 + 32) ^ rs_a)]);
    }
    #pragma unroll
    for(int ni=0;ni<2;ni++){
      int row = wc*32 + ni*16 + lr;
      bfr[ni][0] = ld8(&Bs[row*64 + ((g*8     ) ^ rs_a)]);
      bfr[ni][1] = ld8(&Bs[row*64 + ((g*8 + 32) ^ rs_a)]);
    }
    #pragma unroll
    for(int mi=0;mi<4;mi++)
      #pragma unroll
      for(int ni=0;ni<2;ni++){
        acc[mi][ni] = MFMA(af[mi][0], bfr[ni][0], acc[mi][ni]);
        acc[mi][ni] = MFMA(af[mi][1], bfr[ni][1], acc[mi][ni]);
      }
    __syncthreads();
  }

  float bv[2];
  #pragma unroll
  for(int ni=0;ni<2;ni++) bv[ni] = bias[n0 + wc*32 + ni*16 + lr];
  #pragma unroll
  for(int mi=0;mi<4;mi++){
    int row = m0 + wr*64 + mi*16 + g*4;
    #pragma unroll
    for(int ni=0;ni<2;ni++){
      int col = n0 + wc*32 + ni*16 + lr;
      #pragma unroll
      for(int r=0;r<4;r++){
        float v = acc[mi][ni][r] + bv[ni];
        if constexpr(EPI==0)
          ((u16*)outp)[(size_t)(row + r)*N + col] = f2bf(v);
        else
          res[(size_t)(row + r)*N + col] += v;
      }
    }
  }
}

// ---------------- GEMM 256x256 8-phase (head) — r15/r23 schedule (banked 350us;
// r24's XCD remap regressed FETCH 289->345MB and was reverted)
__global__ __launch_bounds__(512) void k_gemm256(const u16* __restrict__ A,
                                                 const u16* __restrict__ Bt,
                                                 float* __restrict__ out,
                                                 int M, int N, int K, int m_base){
  __shared__ __align__(16) u16 As[2][256*64];
  __shared__ __align__(16) u16 Bs[2][256*64];
  int t = threadIdx.x, l = t & 63, wid = t >> 6;
  int g = l >> 4, lr = l & 15;
  int m0 = m_base + blockIdx.x*256, n0 = blockIdx.y*256;
  f32x4 acc[2][16];
  #pragma unroll
  for(int mi=0;mi<2;mi++)
    #pragma unroll
    for(int i=0;i<16;i++) acc[mi][i] = f32x4{0.f,0.f,0.f,0.f};

  int srow = t >> 3;
  int scol = ((t & 7) ^ (srow & 7)) * 8;
  const int rs = (lr & 7) * 8;
  int nt = K >> 6;

  auto stage_half = [&](int jj, int h){
    int buf = jj & 1; int k0s = jj << 6;
    if(h < 2){
      #pragma unroll
      for(int c=0;c<2;c++){
        int rr = h*128 + c*64 + srow;
        gl_lds16(A + (size_t)(m0 + rr)*K + k0s + scol,
                 &As[buf][rr*64 + (t&7)*8]);
      }
    } else {
      #pragma unroll
      for(int c=0;c<2;c++){
        int rr = (h-2)*128 + c*64 + srow;
        gl_lds16(Bt + (size_t)(n0 + rr)*K + k0s + scol,
                 &Bs[buf][rr*64 + (t&7)*8]);
      }
    }
  };

  stage_half(0,0); stage_half(0,1); stage_half(0,2); stage_half(0,3);
  asm volatile("s_waitcnt vmcnt(2)" ::: "memory");
  __builtin_amdgcn_s_barrier();
  __builtin_amdgcn_sched_barrier(0);

  bf16x8 af[2][2];
  for(int j=0; j<nt; ++j){
    const u16* Ab = As[j & 1];
    const u16* Bb = Bs[j & 1];
    bool pf = (j + 1 < nt);
    #pragma unroll
    for(int q=0; q<4; ++q){
      if(q == 0){
        #pragma unroll
        for(int mi=0;mi<2;mi++){
          int row = wid*32 + mi*16 + lr;
          af[mi][0] = ld8(&Ab[row*64 + ((g*8     ) ^ rs)]);
          af[mi][1] = ld8(&Ab[row*64 + ((g*8 + 32) ^ rs)]);
        }
      }
      bf16x8 bfr[4][2];
      #pragma unroll
      for(int i=0;i<4;i++){
        int row = (q*4 + i)*16 + lr;
        bfr[i][0] = ld8(&Bb[row*64 + ((g*8     ) ^ rs)]);
        bfr[i][1] = ld8(&Bb[row*64 + ((g*8 + 32) ^ rs)]);
      }
      if(pf) stage_half(j+1, q);
      __builtin_amdgcn_s_barrier();
      __builtin_amdgcn_sched_barrier(0);
      __builtin_amdgcn_s_setprio(1);
      #pragma unroll
      for(int mi=0;mi<2;mi++)
        #pragma unroll
        for(int i=0;i<4;i++){
          acc[mi][q*4+i] = MFMA(af[mi][0], bfr[i][0], acc[mi][q*4+i]);
          acc[mi][q*4+i] = MFMA(af[mi][1], bfr[i][1], acc[mi][q*4+i]);
        }
      __builtin_amdgcn_s_setprio(0);
      if(q == 1) asm volatile("s_waitcnt vmcnt(4)" ::: "memory");
      if(q == 3) asm volatile("s_waitcnt vmcnt(2)" ::: "memory");
      __builtin_amdgcn_s_barrier();
      __builtin_amdgcn_sched_barrier(0);
    }
  }

  #pragma unroll
  for(int mi=0;mi<2;mi++){
    int row = m0 + wid*32 + mi*16 + g*4;
    #pragma unroll
    for(int i=0;i<16;i++){
      int col = n0 + i*16 + lr;
      #pragma unroll
      for(int r=0;r<4;r++)
        out[(size_t)(row + r)*N + col] = acc[mi][i][r];
    }
  }
}

// ---------------- head GEMM fallback (small-ws only): BK=32 reg-staged B
__global__ __launch_bounds__(256) void k_gemm_f32b(const u16* __restrict__ A,
                                                   const float* __restrict__ B,
                                                   float* __restrict__ out,
                                                   int M, int N, int K, int m_base){
  __shared__ __align__(16) u16 As[128*32];
  __shared__ __align__(16) u16 Bs[128*32];
  int t = threadIdx.x, l = t & 63, w = t >> 6;
  int g = l >> 4, lr = l & 15;
  int wr = w >> 1, wc = w & 1;
  int m0 = m_base + blockIdx.y*128, n0 = blockIdx.x*128;
  f32x4 acc[4][4];
  #pragma unroll
  for(int i=0;i<4;i++)
    #pragma unroll
    for(int j=0;j<4;j++) acc[i][j] = f32x4{0.f,0.f,0.f,0.f};

  int r0 = t >> 2, c0 = (t & 3)*8;
  const u16* pa0 = A + (size_t)(m0 + r0)*K + c0;
  const u16* pa1 = A + (size_t)(m0 + r0 + 64)*K + c0;
  u16* la0 = As + t*8;  u16* la1 = As + (t+256)*8;
  int br = t >> 1, bc = (t & 1)*16;
  const float* pb = B + (size_t)(n0 + br)*K + bc;

  for(int k0=0; k0<K; k0+=32){
    gl_lds16(pa0, la0); gl_lds16(pa1, la1);
    pa0 += 32; pa1 += 32;
    float4 f0 = ((const float4*)pb)[0];
    float4 f1 = ((const float4*)pb)[1];
    float4 f2 = ((const float4*)pb)[2];
    float4 f3 = ((const float4*)pb)[3];
    pb += 32;
    ushort4 u0{f2bf(f0.x),f2bf(f0.y),f2bf(f0.z),f2bf(f0.w)};
    ushort4 u1{f2bf(f1.x),f2bf(f1.y),f2bf(f1.z),f2bf(f1.w)};
    ushort4 u2{f2bf(f2.x),f2bf(f2.y),f2bf(f2.z),f2bf(f2.w)};
    ushort4 u3{f2bf(f3.x),f2bf(f3.y),f2bf(f3.z),f2bf(f3.w)};
    *(ushort4*)&Bs[br*32 + bc +  0] = u0;
    *(ushort4*)&Bs[br*32 + bc +  4] = u1;
    *(ushort4*)&Bs[br*32 + bc +  8] = u2;
    *(ushort4*)&Bs[br*32 + bc + 12] = u3;
    __syncthreads();
    bf16x8 af[4], bfr[4];
    #pragma unroll
    for(int mi=0;mi<4;mi++) af[mi]  = ld8(&As[(wr*64 + mi*16 + lr)*32 + g*8]);
    #pragma unroll
    for(int ni=0;ni<4;ni++) bfr[ni] = ld8(&Bs[(wc*64 + ni*16 + lr)*32 + g*8]);
    #pragma unroll
    for(int mi=0;mi<4;mi++)
      #pragma unroll
      for(int ni=0;ni<4;ni++)
        acc[mi][ni] = MFMA(af[mi], bfr[ni], acc[mi][ni]);
    __syncthreads();
  }

  #pragma unroll
  for(int mi=0;mi<4;mi++){
    int row = m0 + wr*64 + mi*16 + g*4;
    #pragma unroll
    for(int ni=0;ni<4;ni++){
      int col = n0 + wc*64 + ni*16 + lr;
      #pragma unroll
      for(int r=0;r<4;r++)
        out[(size_t)(row + r)*N + col] = acc[mi][ni][r];
    }
  }
}

// ---------------- flash attention, BALANCED causal pairing (r23-verified):
// grid (16,32); block handles q-tile bx AND q-tile (31-bx) sequentially.
__global__ __launch_bounds__(256) void k_attn(const u16* __restrict__ qkv,
                                              u16* __restrict__ atto){
  __shared__ __align__(16) u16 Ksm[64*72];
  __shared__ __align__(16) u16 Vsm[64*72];
  __shared__ __align__(16) u16 Psm[4][16*72];
  int t = threadIdx.x, l = t & 63, w = t >> 6, g = l >> 4, lr = l & 15;
  int bh = blockIdx.y; int b = bh >> 4, h = bh & 15, kvh = h >> 2;
  const float L2E = 1.44269504088896f;
  const float C1  = 0.125f * L2E;
  float slopeL = exp2f(-0.5f*(float)(h+1)) * L2E;
  float sLkt[4];
  #pragma unroll
  for(int kt=0;kt<4;kt++) sLkt[kt] = slopeL*(float)(kt*16+lr);

  bf16_t onev = (bf16_t)1.0f;
  bf16x8 onesb = {onev,onev,onev,onev,onev,onev,onev,onev};

  int skey = t >> 3, sho = (t & 7)*8;
  int vkey0 = (t>>3)*2, vhd0 = (t&7)*8;
  int4 kreg0, kreg1, vreg0, vreg1;
  auto issue = [&](int kb){
    const u16* kp = qkv + (size_t)(b*2048 + kb*64 + skey)*1536 + 1024 + kvh*64 + sho;
    kreg0 = *(const int4*)kp;
    kreg1 = *(const int4*)(kp + (size_t)32*1536);
    const u16* v0 = qkv + (size_t)(b*2048 + kb*64 + vkey0)*1536 + 1280 + kvh*64 + vhd0;
    vreg0 = *(const int4*)v0;
    vreg1 = *(const int4*)(v0 + 1536);
  };

  #pragma unroll
  for(int pass=0; pass<2; pass++){
    int qt = (pass == 0) ? blockIdx.x : (31 - blockIdx.x);
    int qb = qt*64;
    const u16* qp = qkv + (size_t)(b*2048 + qb + w*16 + lr)*1536 + h*64;
    bf16x8 qf0 = ld8(qp + g*8);
    bf16x8 qf1 = ld8(qp + 32 + g*8);

    f32x4 oacc[4];
    #pragma unroll
    for(int i=0;i<4;i++) oacc[i] = f32x4{0.f,0.f,0.f,0.f};
    f32x4 lsum = f32x4{0.f,0.f,0.f,0.f};

    int qmin_w = qb + w*16;
    int qmax_w = qmin_w + 15;
    int nkb = qt + 1;
    issue(0);
    for(int kb=0; kb<nkb; kb++){
      __syncthreads();
      *(int4*)&Ksm[skey*72 + sho] = kreg0;
      *(int4*)&Ksm[(skey+32)*72 + sho] = kreg1;
      {
        const u16* ua = (const u16*)&vreg0; const u16* ub = (const u16*)&vreg1;
        #pragma unroll
        for(int j=0;j<8;j++){
          int row = vhd0 + j;
          int colp = vkey0 ^ ((row>>3)*8);
          unsigned pr = (unsigned)ua[j] | ((unsigned)ub[j]<<16);
          *(unsigned*)&Vsm[row*72 + colp] = pr;
        }
      }
      __syncthreads();
      if(kb + 1 < nkb) issue(kb + 1);
      if(kb*64 > qmax_w) continue;
      f32x4 sacc[4];
      #pragma unroll
      for(int kt=0;kt<4;kt++) sacc[kt] = f32x4{0.f,0.f,0.f,0.f};
      #pragma unroll
      for(int kt=0;kt<4;kt++){
        bf16x8 kf0 = ld8(&Ksm[(kt*16+lr)*72 + g*8]);
        bf16x8 kf1 = ld8(&Ksm[(kt*16+lr)*72 + 32 + g*8]);
        sacc[kt] = MFMA(qf0, kf0, sacc[kt]);
        sacc[kt] = MFMA(qf1, kf1, sacc[kt]);
      }
      if(kb*64 + 63 <= qmin_w){
        #pragma unroll
        for(int r=0;r<4;r++){
          int q = qb + w*16 + g*4 + r;
          float base = slopeL*(float)(kb*64 - q) - 8.0f*L2E;
          #pragma unroll
          for(int kt=0;kt<4;kt++){
            float f = fmaf(sacc[kt][r], C1, base + sLkt[kt]);
            Psm[w][(g*4+r)*72 + kt*16 + lr] = f2bf(exp2f(f));
          }
        }
      } else {
        #pragma unroll
        for(int r=0;r<4;r++){
          int q = qb + w*16 + g*4 + r;
          float base = slopeL*(float)(kb*64 - q) - 8.0f*L2E;
          #pragma unroll
          for(int kt=0;kt<4;kt++){
            int key = kb*64 + kt*16 + lr;
            float f = fmaf(sacc[kt][r], C1, base + sLkt[kt]);
            float p = (key <= q) ? exp2f(f) : 0.f;
            Psm[w][(g*4+r)*72 + kt*16 + lr] = f2bf(p);
          }
        }
      }
      #pragma unroll
      for(int ks=0;ks<2;ks++){
        bf16x8 pf = ld8(&Psm[w][lr*72 + ks*32 + g*8]);
        lsum = MFMA(pf, onesb, lsum);
        #pragma unroll
        for(int ht=0;ht<4;ht++){
          int row = ht*16 + lr;
          int colp = (ks*32 + g*8) ^ ((row>>3)*8);
          bf16x8 vf = ld8(&Vsm[row*72 + colp]);
          oacc[ht] = MFMA(pf, vf, oacc[ht]);
        }
      }
    }
    #pragma unroll
    for(int ht=0;ht<4;ht++){
      #pragma unroll
      for(int r=0;r<4;r++){
        float o = oacc[ht][r] / lsum[r];
        atto[(size_t)(b*2048 + qb + w*16 + g*4 + r)*1024 + h*64 + ht*16 + lr] = f2bf(o);
      }
    }
  }
}

extern "C" void kernel_launch(void* const* d_in, const int* in_sizes, int n_in,
                              void* d_out, int out_size, void* d_ws, size_t ws_size,
                              hipStream_t stream) {
  const float* tok_emb = (const float*)d_in[0];
  const float* ln1_s   = (const float*)d_in[1];
  const float* ln1_b   = (const float*)d_in[2];
  const float* qkv_w   = (const float*)d_in[3];
  const float* qkv_b   = (const float*)d_in[4];
  const float* proj_w  = (const float*)d_in[5];
  const float* proj_b  = (const float*)d_in[6];
  const float* ln2_s   = (const float*)d_in[7];
  const float* ln2_b   = (const float*)d_in[8];
  const float* fc1_w   = (const float*)d_in[9];
  const float* fc1_b   = (const float*)d_in[10];
  const float* fc2_w   = (const float*)d_in[11];
  const float* fc2_b   = (const float*)d_in[12];
  const float* lnf_s   = (const float*)d_in[13];
  const float* lnf_b   = (const float*)d_in[14];
  const int*   idx     = (const int*)d_in[15];

  // scratch plan inside d_out (524 MB, f32 logits written last):
  char* ob = (char*)d_out;
  float* xf32  = (float*)(ob);                                 //  0   .. 16.8 MB
  u16* qkv_bf  = (u16*)(ob + (size_t)16777216);                // 16.8 .. 29.4
  u16* atto_bf = (u16*)(ob + (size_t)29360128);                // 29.4 .. 37.7
  u16* mid_bf  = (u16*)(ob + (size_t)37748736);                // 37.7 .. 71.3
  u16* wt_qkv  = (u16*)(ob + (size_t)71303168);                // 71.3 .. 83.9
  u16* wt_proj = (u16*)(ob + (size_t)83886080);                // 83.9 .. 92.3
  u16* wt_fc1  = (u16*)(ob + (size_t)92274688);                // 92.3 ..125.8
  u16* wt_fc2  = (u16*)(ob + (size_t)125829120);               //125.8 ..159.4
  u16* h_bf    = (u16*)d_ws;                                   //  8.4 MB
  float* out   = (float*)d_out;

  bool big_ws = ws_size >= (size_t)(8388608 + 65536000);
  u16* te_bf = big_ws ? (u16*)((char*)d_ws + 8388608)
                      : (u16*)(ob + (size_t)294912000);

  k_prep<<<36096, 256, 0, stream>>>(tok_emb, te_bf, idx, xf32);
  k_convT<<<dim3(24,16,4), 256, 0, stream>>>(qkv_w,  wt_qkv, 1024, 1536);
  k_convT<<<dim3(16,16,4), 256, 0, stream>>>(proj_w, wt_proj, 1024, 1024);
  k_convT<<<dim3(64,16,4), 256, 0, stream>>>(fc1_w, wt_fc1, 1024, 4096);
  k_convT<<<dim3(16,64,4), 256, 0, stream>>>(fc2_w, wt_fc2, 4096, 1024);

  for(int l=0; l<4; l++){
    k_ln<<<4096, 256, 0, stream>>>(xf32, ln1_s + (size_t)l*1024, ln1_b + (size_t)l*1024, h_bf);
    k_gemm_n64<0><<<dim3(24,32), 256, 0, stream>>>(h_bf, wt_qkv + (size_t)l*1536*1024,
                                                   qkv_b + (size_t)l*1536,
                                                   qkv_bf, nullptr, 4096, 1536, 1024);
    k_attn<<<dim3(16,32), 256, 0, stream>>>(qkv_bf, atto_bf);
    k_gemm_n64<1><<<dim3(16,32), 256, 0, stream>>>(atto_bf, wt_proj + (size_t)l*1024*1024,
                                                   proj_b + (size_t)l*1024,
                                                   nullptr, xf32, 4096, 1024, 1024);
    k_ln<<<4096, 256, 0, stream>>>(xf32, ln2_s + (size_t)l*1024, ln2_b + (size_t)l*1024, h_bf);
    k_gemm<2,0><<<dim3(32,32), 256, 0, stream>>>(h_bf, wt_fc1 + (size_t)l*4096*1024,
                                                 fc1_b + (size_t)l*4096,
                                                 mid_bf, nullptr, 4096, 4096, 1024, 0);
    k_gemm_n64<1><<<dim3(16,32), 256, 0, stream>>>(mid_bf, wt_fc2 + (size_t)l*1024*4096,
                                                   fc2_b + (size_t)l*1024,
                                                   nullptr, xf32, 4096, 1024, 4096);
  }
  k_ln<<<4096, 256, 0, stream>>>(xf32, lnf_s, lnf_b, h_bf);

  if(big_ws){
    k_gemm256<<<dim3(16,125), 512, 0, stream>>>(h_bf, te_bf, out,
                                                4096, 32000, 1024, 0);
  } else {
    k_gemm256<<<dim3(9,125), 512, 0, stream>>>(h_bf, te_bf, out,
                                               4096, 32000, 1024, 0);
    k_gemm256<<<dim3(5,125), 512, 0, stream>>>(h_bf, te_bf, out,
                                               4096, 32000, 1024, 2816);
    k_gemm_f32b<<<dim3(250,4), 256, 0, stream>>>(h_bf, tok_emb, out,
                                                 4096, 32000, 1024, 2304);
  }
}